// Round 20
// baseline (314.612 us; speedup 1.0000x reference)
//
#include <hip/hip_runtime.h>
#include <hip/hip_bf16.h>
#include <math.h>

#define Tn 1024
#define Cn 960
#define Hn 15
#define Nn 64
#define Mn 4096  // B*T

typedef short bf16x8 __attribute__((ext_vector_type(8)));
typedef float f32x4 __attribute__((ext_vector_type(4)));

#define MCc ((size_t)Mn * Cn)

__device__ __forceinline__ float sigmf(float x) { return 1.0f / (1.0f + __expf(-x)); }

// round-to-nearest-even f32 -> bf16 (as ushort)
__device__ __forceinline__ ushort f2bf(float x) {
    unsigned u = __float_as_uint(x);
    unsigned r = (u + 0x7FFFu + ((u >> 16) & 1u)) >> 16;
    return (ushort)r;
}
__device__ __forceinline__ float bf2f(ushort h) { return __uint_as_float(((unsigned)h) << 16); }

// full sum over the 16-lane DPP row via row_ror rotate-accumulate (all VALU).
__device__ __forceinline__ float rowsum16(float x) {
    x += __int_as_float(__builtin_amdgcn_update_dpp(0, __float_as_int(x), 0x121, 0xF, 0xF, true)); // ror:1
    x += __int_as_float(__builtin_amdgcn_update_dpp(0, __float_as_int(x), 0x122, 0xF, 0xF, true)); // ror:2
    x += __int_as_float(__builtin_amdgcn_update_dpp(0, __float_as_int(x), 0x124, 0xF, 0xF, true)); // ror:4
    x += __int_as_float(__builtin_amdgcn_update_dpp(0, __float_as_int(x), 0x128, 0xF, 0xF, true)); // ror:8
    return x;
}

// async global->LDS, 16B per lane; LDS dest = wave-uniform base + lane*16
#define GLOAD16(GPTR, LPTR)                                                   \
    __builtin_amdgcn_global_load_lds(                                         \
        (const __attribute__((address_space(1))) unsigned*)(GPTR),            \
        (__attribute__((address_space(3))) unsigned*)(LPTR), 16, 0, 0)

// ---------------------------------------------------------------------------
// token-shift + 6 mixes; ALL six emitted as split-bf16 pairs (hi @p, lo @p+MC)
// ---------------------------------------------------------------------------
__global__ __launch_bounds__(256) void mix6_kernel(
    const float* __restrict__ x,
    const float* __restrict__ mr, const float* __restrict__ mw, const float* __restrict__ mk,
    const float* __restrict__ mv, const float* __restrict__ ma, const float* __restrict__ mg,
    ushort* __restrict__ r_sp, ushort* __restrict__ w_sp, ushort* __restrict__ k_sp,
    ushort* __restrict__ v_sp, ushort* __restrict__ a_sp, ushort* __restrict__ g_sp)
{
    int idx = blockIdx.x * 256 + threadIdx.x;  // float4 index
    int e = idx * 4;
    if (e >= Mn * Cn) return;
    int m = e / Cn;
    int c = e - m * Cn;
    int t = m & (Tn - 1);
    float4 xv = *(const float4*)(x + e);
    float4 xp = make_float4(0.f, 0.f, 0.f, 0.f);
    if (t > 0) xp = *(const float4*)(x + e - Cn);
    float4 dx = make_float4(xp.x - xv.x, xp.y - xv.y, xp.z - xv.z, xp.w - xv.w);
#define MIXSPLIT(MIXP, P)                                                     \
    {                                                                         \
        float4 mm = *(const float4*)(MIXP + c);                               \
        float4 O = make_float4(xv.x + dx.x * mm.x, xv.y + dx.y * mm.y,        \
                               xv.z + dx.z * mm.z, xv.w + dx.w * mm.w);       \
        ushort h0 = f2bf(O.x), h1 = f2bf(O.y), h2 = f2bf(O.z), h3 = f2bf(O.w);\
        ushort l0 = f2bf(O.x - bf2f(h0)), l1 = f2bf(O.y - bf2f(h1));          \
        ushort l2 = f2bf(O.z - bf2f(h2)), l3 = f2bf(O.w - bf2f(h3));          \
        *(ushort4*)(P + e) = make_ushort4(h0, h1, h2, h3);                    \
        *(ushort4*)(P + MCc + e) = make_ushort4(l0, l1, l2, l3);              \
    }
    MIXSPLIT(mr, r_sp)
    MIXSPLIT(mw, w_sp)
    MIXSPLIT(mk, k_sp)
    MIXSPLIT(mv, v_sp)
    MIXSPLIT(ma, a_sp)
    MIXSPLIT(mg, g_sp)
#undef MIXSPLIT
}

// ---------------------------------------------------------------------------
// transpose + split-convert weight [960][960] -> [N][K] hi/lo (single)
// ---------------------------------------------------------------------------
__global__ __launch_bounds__(256) void convWT_kernel(
    const float* __restrict__ W, ushort* __restrict__ Thi, ushort* __restrict__ Tlo)
{
    __shared__ float tile[32][33];
    int k0 = blockIdx.x * 32, n0 = blockIdx.y * 32;
    int tx = threadIdx.x & 31, ty = threadIdx.x >> 5;  // 32 x 8
#pragma unroll
    for (int i = 0; i < 4; ++i)
        tile[ty + 8 * i][tx] = W[(size_t)(k0 + ty + 8 * i) * 960 + n0 + tx];
    __syncthreads();
#pragma unroll
    for (int i = 0; i < 4; ++i) {
        float x = tile[tx][ty + 8 * i];
        ushort h = f2bf(x);
        ushort l = f2bf(x - bf2f(h));
        size_t o = (size_t)(n0 + ty + 8 * i) * 960 + k0 + tx;
        Thi[o] = h;
        Tlo[o] = l;
    }
}

// merged z=3: Wr->S0, Wk->S1, Wv->S2
__global__ __launch_bounds__(256) void convWT3_kernel(
    const float* __restrict__ Wr, const float* __restrict__ Wk,
    const float* __restrict__ Wv,
    ushort* __restrict__ S0, ushort* __restrict__ S1, ushort* __restrict__ S2)
{
    __shared__ float tile[32][33];
    int z = blockIdx.z;
    const float* W = (z == 0) ? Wr : (z == 1) ? Wk : Wv;
    ushort* Thi = (z == 0) ? S0 : (z == 1) ? S1 : S2;
    ushort* Tlo = Thi + (size_t)960 * 960;
    int k0 = blockIdx.x * 32, n0 = blockIdx.y * 32;
    int tx = threadIdx.x & 31, ty = threadIdx.x >> 5;
#pragma unroll
    for (int i = 0; i < 4; ++i)
        tile[ty + 8 * i][tx] = W[(size_t)(k0 + ty + 8 * i) * 960 + n0 + tx];
    __syncthreads();
#pragma unroll
    for (int i = 0; i < 4; ++i) {
        float x = tile[tx][ty + 8 * i];
        ushort h = f2bf(x);
        ushort l = f2bf(x - bf2f(h));
        size_t o = (size_t)(n0 + ty + 8 * i) * 960 + k0 + tx;
        Thi[o] = h;
        Tlo[o] = l;
    }
}

// ---------------------------------------------------------------------------
// LoRA weight prep
// ---------------------------------------------------------------------------
__global__ __launch_bounds__(256) void wprep_kernel(
    const float* __restrict__ w1, const float* __restrict__ a1,
    const float* __restrict__ v1, const float* __restrict__ g1,
    const float* __restrict__ w2, const float* __restrict__ a2,
    const float* __restrict__ v2, const float* __restrict__ g2,
    ushort* __restrict__ arena)
{
    __shared__ float tile[32][33];
    int z = blockIdx.z;
    const float* src;
    int K, N;
    size_t off;
    switch (z) {
        case 0: src = w1; K = 960; N = 64;  off = 0;      break;
        case 1: src = a1; K = 960; N = 64;  off = 122880; break;
        case 2: src = v1; K = 960; N = 32;  off = 245760; break;
        case 3: src = g1; K = 960; N = 128; off = 307200; break;
        case 4: src = w2; K = 64;  N = 960; off = 552960; break;
        case 5: src = a2; K = 64;  N = 960; off = 675840; break;
        case 6: src = v2; K = 32;  N = 960; off = 798720; break;
        default: src = g2; K = 128; N = 960; off = 860160; break;
    }
    int k0 = blockIdx.x * 32, n0 = blockIdx.y * 32;
    if (k0 >= K || n0 >= N) return;
    int tx = threadIdx.x & 31, ty = threadIdx.x >> 5;
#pragma unroll
    for (int i = 0; i < 4; ++i)
        tile[ty + 8 * i][tx] = src[(size_t)(k0 + ty + 8 * i) * N + n0 + tx];
    __syncthreads();
    ushort* Thi = arena + off;
    ushort* Tlo = arena + off + (size_t)K * N;
#pragma unroll
    for (int i = 0; i < 4; ++i) {
        float x = tile[tx][ty + 8 * i];
        ushort h = f2bf(x);
        ushort l = f2bf(x - bf2f(h));
        size_t o = (size_t)(n0 + ty + 8 * i) * K + k0 + tx;
        Thi[o] = h;
        Tlo[o] = l;
    }
}

// ---------------------------------------------------------------------------
// split-convert arbitrary f32 array -> hi/lo bf16
// ---------------------------------------------------------------------------
__global__ __launch_bounds__(256) void convN_kernel(
    const float* __restrict__ X, ushort* __restrict__ hi, ushort* __restrict__ lo, int n4)
{
    int idx = blockIdx.x * 256 + threadIdx.x;
    if (idx >= n4) return;
    int e = idx * 4;
    float4 x = *(const float4*)(X + e);
    ushort h0 = f2bf(x.x), h1 = f2bf(x.y), h2 = f2bf(x.z), h3 = f2bf(x.w);
    ushort l0 = f2bf(x.x - bf2f(h0)), l1 = f2bf(x.y - bf2f(h1));
    ushort l2 = f2bf(x.z - bf2f(h2)), l3 = f2bf(x.w - bf2f(h3));
    *(ushort4*)(hi + e) = make_ushort4(h0, h1, h2, h3);
    *(ushort4*)(lo + e) = make_ushort4(l0, l1, l2, l3);
}

// ---------------------------------------------------------------------------
// split-bf16 MFMA GEMM core, 256 threads / 4 waves, BM=128 BN=64 BK=32.
// global_load_lds staging with XOR-SWIZZLED layout (rule #21: linear DMA
// dest + pre-swizzled GLOBAL source + matching swizzled ds_read):
//   LDS[row][cp] = G[row][cp ^ ((row>>1)&3)]  (cp = 16B chunk in 64B row)
//   write: lane l fetches global chunk (l&3)^((l>>3)&3) of row l>>2
//   read:  chunk lk ^ ((lr>>1)&3)  -> per-quarter-wave banks spread 8-wide,
//   2 lanes/4-bank group = conflict-free b128 (was 8-way, 8.3M conflicts).
// 48KB LDS -> 3 blocks/CU.  1-barrier K loop (issue k+1 DMA, compute k).
// ---------------------------------------------------------------------------
__device__ __forceinline__ void gemm_core(
    const ushort* __restrict__ Ahi, const ushort* __restrict__ Alo,
    const ushort* __restrict__ Bhi, const ushort* __restrict__ Blo,
    float* __restrict__ C, int ldc, int bm, int bn)
{
    __shared__ __align__(16) ushort sA[2][2][128][32];  // 32768 B
    __shared__ __align__(16) ushort sB[2][2][64][32];   // 16384 B
    const int K = 960;
    int t = threadIdx.x;
    int w = t >> 6, l = t & 63;
    int lr = l & 15, lk = l >> 4;
    int lks = lk ^ ((lr >> 1) & 3);   // swizzled read chunk

    // staging: lane covers row l>>2; SOURCE chunk pre-swizzled so linear
    // DMA lands the swizzled layout
    int srow = l >> 2;
    int skc = ((l & 3) ^ ((l >> 3) & 3)) * 8;
    const ushort* gA0h = Ahi + (size_t)(bm + 32 * w + srow) * K + skc;
    const ushort* gA1h = Ahi + (size_t)(bm + 32 * w + 16 + srow) * K + skc;
    const ushort* gA0l = Alo + (size_t)(bm + 32 * w + srow) * K + skc;
    const ushort* gA1l = Alo + (size_t)(bm + 32 * w + 16 + srow) * K + skc;
    const ushort* gBh = Bhi + (size_t)(bn + 16 * w + srow) * K + skc;
    const ushort* gBl = Blo + (size_t)(bn + 16 * w + srow) * K + skc;

    f32x4 acc[2][4];
#pragma unroll
    for (int i = 0; i < 2; ++i)
#pragma unroll
        for (int j = 0; j < 4; ++j)
#pragma unroll
            for (int e = 0; e < 4; ++e) acc[i][j][e] = 0.f;

#define STAGE(BUF, KOFF)                                                      \
    {                                                                         \
        GLOAD16(gA0h + (KOFF), &sA[BUF][0][32 * w][0]);                       \
        GLOAD16(gA1h + (KOFF), &sA[BUF][0][32 * w + 16][0]);                  \
        GLOAD16(gA0l + (KOFF), &sA[BUF][1][32 * w][0]);                       \
        GLOAD16(gA1l + (KOFF), &sA[BUF][1][32 * w + 16][0]);                  \
        GLOAD16(gBh + (KOFF), &sB[BUF][0][16 * w][0]);                        \
        GLOAD16(gBl + (KOFF), &sB[BUF][1][16 * w][0]);                        \
    }
#define COMPUTEK(BUF)                                                         \
    {                                                                         \
        bf16x8 ah[2], al[2], bh[4], bl[4];                                    \
        _Pragma("unroll")                                                     \
        for (int i = 0; i < 2; ++i) {                                         \
            ah[i] = *(const bf16x8*)&sA[BUF][0][32 * w + 16 * i + lr][lks * 8];\
            al[i] = *(const bf16x8*)&sA[BUF][1][32 * w + 16 * i + lr][lks * 8];\
        }                                                                     \
        _Pragma("unroll")                                                     \
        for (int j = 0; j < 4; ++j) {                                         \
            bh[j] = *(const bf16x8*)&sB[BUF][0][16 * j + lr][lks * 8];        \
            bl[j] = *(const bf16x8*)&sB[BUF][1][16 * j + lr][lks * 8];        \
        }                                                                     \
        _Pragma("unroll")                                                     \
        for (int i = 0; i < 2; ++i)                                           \
            _Pragma("unroll")                                                 \
            for (int j = 0; j < 4; ++j) {                                     \
                acc[i][j] = __builtin_amdgcn_mfma_f32_16x16x32_bf16(          \
                    ah[i], bh[j], acc[i][j], 0, 0, 0);                        \
                acc[i][j] = __builtin_amdgcn_mfma_f32_16x16x32_bf16(          \
                    ah[i], bl[j], acc[i][j], 0, 0, 0);                        \
                acc[i][j] = __builtin_amdgcn_mfma_f32_16x16x32_bf16(          \
                    al[i], bh[j], acc[i][j], 0, 0, 0);                        \
            }                                                                 \
    }

    STAGE(0, 0)
    asm volatile("s_waitcnt vmcnt(0)" ::: "memory");
    __builtin_amdgcn_s_barrier();

    int cur = 0;
    for (int ks = 0; ks < 30; ++ks) {
        if (ks + 1 < 30) STAGE(cur ^ 1, (ks + 1) * 32)
        COMPUTEK(cur)
        asm volatile("s_waitcnt vmcnt(0) lgkmcnt(0)" ::: "memory");
        __builtin_amdgcn_s_barrier();
        cur ^= 1;
    }

#pragma unroll
    for (int i = 0; i < 2; ++i)
#pragma unroll
        for (int j = 0; j < 4; ++j)
#pragma unroll
            for (int jr = 0; jr < 4; ++jr) {
                int row = bm + 32 * w + 16 * i + lk * 4 + jr;
                int col = bn + 16 * j + lr;
                C[(size_t)row * ldc + col] = acc[i][j][jr];
            }
#undef COMPUTEK
#undef STAGE
}

// merged stage-1: z=0 r, z=1 k, z=2 v
__global__ __launch_bounds__(256) void gemm3_kernel(
    const ushort* __restrict__ XR, const ushort* __restrict__ XK,
    const ushort* __restrict__ XV,
    const ushort* __restrict__ WrS, const ushort* __restrict__ WkS,
    const ushort* __restrict__ WvS,
    float* __restrict__ oR, float* __restrict__ oK, float* __restrict__ oV)
{
    int z = blockIdx.z;
    const ushort* A = (z == 0) ? XR : (z == 1) ? XK : XV;
    const ushort* W = (z == 0) ? WrS : (z == 1) ? WkS : WvS;
    float* C = (z == 0) ? oR : (z == 1) ? oK : oV;
    gemm_core(A, A + MCc, W, W + (size_t)960 * 960, C, Cn,
              blockIdx.x * 128, blockIdx.y * 64);
}

__global__ __launch_bounds__(256) void gemm1_kernel(
    const ushort* __restrict__ Ahi, const ushort* __restrict__ Alo,
    const ushort* __restrict__ Bhi, const ushort* __restrict__ Blo,
    float* __restrict__ C, int ldc)
{
    gemm_core(Ahi, Alo, Bhi, Blo, C, ldc, blockIdx.x * 128, blockIdx.y * 64);
}

// ---------------------------------------------------------------------------
// generic split-bf16 MFMA core for LoRA (512 threads) — unchanged
// ---------------------------------------------------------------------------
__device__ __forceinline__ void lora_core(
    const ushort* __restrict__ Ahi, const ushort* __restrict__ Alo, int lda,
    const ushort* __restrict__ Bhi, const ushort* __restrict__ Blo,
    float* __restrict__ C, int ldc, int Nvalid, int K, int act, int bn)
{
    __shared__ __align__(16) ushort sA[2][2][128][40];
    __shared__ __align__(16) ushort sB[2][2][64][40];
    int bm = blockIdx.x * 128;
    int t = threadIdx.x;
    int w = t >> 6, l = t & 63;
    int lr = l & 15, lk = l >> 4;

    int ar = t >> 2, aseg = t & 3;
    int brr = t >> 2;
    int bhl = brr >> 6, brow = brr & 63, bseg = t & 3;
    const ushort* gAh = Ahi + (size_t)(bm + ar) * lda + aseg * 8;
    const ushort* gAl = Alo + (size_t)(bm + ar) * lda + aseg * 8;
    const ushort* gB = (bhl ? Blo : Bhi) + (size_t)(bn + brow) * K + bseg * 8;

    f32x4 acc[4];
#pragma unroll
    for (int j = 0; j < 4; ++j)
#pragma unroll
        for (int e = 0; e < 4; ++e) acc[j][e] = 0.f;

    float4 rhP, rlP, rbP, rhQ, rlQ, rbQ;
#define LLOADP(KOFF)                                                          \
    {                                                                         \
        rhP = *(const float4*)(gAh + (KOFF));                                 \
        rlP = *(const float4*)(gAl + (KOFF));                                 \
        rbP = *(const float4*)(gB + (KOFF));                                  \
    }
#define LLOADQ(KOFF)                                                          \
    {                                                                         \
        rhQ = *(const float4*)(gAh + (KOFF));                                 \
        rlQ = *(const float4*)(gAl + (KOFF));                                 \
        rbQ = *(const float4*)(gB + (KOFF));                                  \
    }
#define LWRITEP(BUF)                                                          \
    {                                                                         \
        *(float4*)&sA[BUF][0][ar][aseg * 8] = rhP;                            \
        *(float4*)&sA[BUF][1][ar][aseg * 8] = rlP;                            \
        *(float4*)&sB[BUF][bhl][brow][bseg * 8] = rbP;                        \
    }
#define LWRITEQ(BUF)                                                          \
    {                                                                         \
        *(float4*)&sA[BUF][0][ar][aseg * 8] = rhQ;                            \
        *(float4*)&sA[BUF][1][ar][aseg * 8] = rlQ;                            \
        *(float4*)&sB[BUF][bhl][brow][bseg * 8] = rbQ;                        \
    }
#define LCOMPUTE(BUF)                                                         \
    {                                                                         \
        bf16x8 ah, al, bh[4], bl[4];                                          \
        ah = *(const bf16x8*)&sA[BUF][0][16 * w + lr][lk * 8];                \
        al = *(const bf16x8*)&sA[BUF][1][16 * w + lr][lk * 8];                \
        _Pragma("unroll")                                                     \
        for (int j = 0; j < 4; ++j) {                                         \
            bh[j] = *(const bf16x8*)&sB[BUF][0][16 * j + lr][lk * 8];         \
            bl[j] = *(const bf16x8*)&sB[BUF][1][16 * j + lr][lk * 8];         \
        }                                                                     \
        _Pragma("unroll")                                                     \
        for (int j = 0; j < 4; ++j) {                                         \
            acc[j] = __builtin_amdgcn_mfma_f32_16x16x32_bf16(ah, bh[j], acc[j], 0, 0, 0); \
            acc[j] = __builtin_amdgcn_mfma_f32_16x16x32_bf16(ah, bl[j], acc[j], 0, 0, 0); \
            acc[j] = __builtin_amdgcn_mfma_f32_16x16x32_bf16(al, bh[j], acc[j], 0, 0, 0); \
        }                                                                     \
    }

    int nk = K >> 5;
    LLOADP(0)
    LWRITEP(0)
    if (nk > 1) LLOADQ(32)
    asm volatile("s_waitcnt lgkmcnt(0)" ::: "memory");
    __builtin_amdgcn_s_barrier();

    int cur = 0;
    for (int ks = 0; ks < nk; ++ks) {
        int k2 = (ks + 2 < nk ? ks + 2 : nk - 1) * 32;
        if (!(ks & 1)) { LLOADP(k2) } else { LLOADQ(k2) }
        LCOMPUTE(cur)
        if (ks + 1 < nk) {
            if (!(ks & 1)) { LWRITEQ(cur ^ 1) } else { LWRITEP(cur ^ 1) }
            asm volatile("s_waitcnt lgkmcnt(0)" ::: "memory");
            __builtin_amdgcn_s_barrier();
        }
        cur ^= 1;
    }

#pragma unroll
    for (int j = 0; j < 4; ++j)
#pragma unroll
        for (int jr = 0; jr < 4; ++jr) {
            int row = bm + 16 * w + lk * 4 + jr;
            int col = bn + 16 * j + lr;
            if (col < Nvalid) {
                float v = acc[j][jr];
                if (act == 1) v = tanhf(v);
                else if (act == 2) v = sigmf(v);
                C[(size_t)row * ldc + col] = v;
            }
        }
#undef LCOMPUTE
#undef LWRITEP
#undef LWRITEQ
#undef LLOADP
#undef LLOADQ
}

// LoRA-down MFMA: grid (32, 2, 4)
__global__ __launch_bounds__(512) void lora_down_kernel(
    const ushort* __restrict__ xw_sp, const ushort* __restrict__ xa_sp,
    const ushort* __restrict__ xv_sp, const ushort* __restrict__ xg_sp,
    const ushort* __restrict__ arena, float* __restrict__ hid)
{
    int z = blockIdx.z;
    int bn = blockIdx.y * 64;
    const ushort* A;
    size_t off;
    int N, act, coff;
    switch (z) {
        case 0: A = xw_sp; off = 0;      N = 64;  act = 1; coff = 0;   break;
        case 1: A = xa_sp; off = 122880; N = 64;  act = 0; coff = 64;  break;
        case 2: A = xv_sp; off = 245760; N = 32;  act = 0; coff = 128; break;
        default: A = xg_sp; off = 307200; N = 128; act = 2; coff = 160; break;
    }
    if (bn >= N) return;
    lora_core(A, A + MCc, Cn, arena + off, arena + off + (size_t)960 * N,
              hid + coff, 288, N, 960, act, bn);
}

// LoRA-up MFMA: grid (32, 15, 4)
__global__ __launch_bounds__(512) void lora_up_kernel(
    const ushort* __restrict__ hidHi, const ushort* __restrict__ hidLo,
    const ushort* __restrict__ arena,
    float* __restrict__ oW, float* __restrict__ oA,
    float* __restrict__ oV, float* __restrict__ oG)
{
    int z = blockIdx.z;
    int bn = blockIdx.y * 64;
    size_t off;
    int K, aoff;
    float* C;
    switch (z) {
        case 0: off = 552960; K = 64;  aoff = 0;   C = oW; break;
        case 1: off = 675840; K = 64;  aoff = 64;  C = oA; break;
        case 2: off = 798720; K = 32;  aoff = 128; C = oV; break;
        default: off = 860160; K = 128; aoff = 160; C = oG; break;
    }
    lora_core(hidHi + aoff, hidLo + aoff, 288, arena + off,
              arena + off + (size_t)K * 960, C, Cn, Cn, K, 0, bn);
}

// ---------------------------------------------------------------------------
// SEQUENCE-PARALLEL chunked scan: 8 segments (480 blocks), 16-step chunks,
// 48-step warmup.  (R19 config, ~104us.)
// ---------------------------------------------------------------------------
__global__ __launch_bounds__(256, 2) void scan_kernel(
    const float* __restrict__ rP, const float* __restrict__ wrawP,
    const float* __restrict__ apreP, const float* __restrict__ vsigP,
    const float* __restrict__ krawP, const float* __restrict__ vrawP,
    const float* __restrict__ vfirstP, const float* __restrict__ gP,
    const float* __restrict__ w0, const float* __restrict__ a0,
    const float* __restrict__ v0c, const float* __restrict__ kkc,
    const float* __restrict__ kac, const float* __restrict__ r_k,
    const float* __restrict__ ln_g, const float* __restrict__ ln_b,
    ushort* __restrict__ xsp)
{
    __shared__ float buf[2][7][16][64];  // 57344 B
    __shared__ float outL[16][64];       // 4096 B
    int tid = threadIdx.x;
    int q = tid >> 6, l = tid & 63;
    int blk = blockIdx.x;
    int bh = blk >> 3, seg = blk & 7;
    int bb = bh / Hn, h = bh - bb * Hn;
    size_t base = (size_t)bb * Tn * Cn + h * 64;
    int rg = l >> 4, cg = l & 15;
    int row0 = 16 * q + 4 * rg;
    int c0 = 4 * cg;

    int sstep = tid >> 4, sseg = tid & 15;
    size_t soff = base + (size_t)sstep * Cn + sseg * 4;
    int wofs = sstep * 64 + sseg * 4;
    int ccol = h * 64 + sseg * 4;

    int cbeg = (seg == 0) ? 0 : 8 * seg - 3;
    int cendc = 8 * seg + 8;
    int coutc = 8 * seg;

    float4 w0c4 = *(const float4*)(w0 + ccol);
    float4 a0c4 = *(const float4*)(a0 + ccol);
    float4 v0c4 = *(const float4*)(v0c + ccol);
    float4 kkc4 = *(const float4*)(kkc + ccol);
    float4 kac4 = *(const float4*)(kac + ccol);
    float4 rk4 = *(const float4*)(r_k + ccol);
    float4 lg4 = *(const float4*)(ln_g + ccol);
    float4 lb4 = *(const float4*)(ln_b + ccol);

    float s[4][4];
#pragma unroll
    for (int r = 0; r < 4; ++r)
#pragma unroll
        for (int c = 0; c < 4; ++c) s[r][c] = 0.f;

    float4 g_r, g_wr, g_vr, g_vf, g_vs, g_g, g_kr, g_ap;

#define LOADSTAGE(OFF)                                                        \
    g_r = *(const float4*)(rP + soff + (OFF));                                \
    g_wr = *(const float4*)(wrawP + soff + (OFF));                            \
    g_vr = *(const float4*)(vrawP + soff + (OFF));                            \
    g_vf = *(const float4*)(vfirstP + soff + (OFF));                          \
    g_vs = *(const float4*)(vsigP + soff + (OFF));                            \
    g_g = *(const float4*)(gP + soff + (OFF));                                \
    g_kr = *(const float4*)(krawP + soff + (OFF));                            \
    g_ap = *(const float4*)(apreP + soff + (OFF));

#define PARK(BN)                                                              \
    {                                                                         \
        const float E = 0.60653065971263342f;                                 \
        float4 w4;                                                            \
        w4.x = sigmf(w0c4.x + g_wr.x) * E;                                    \
        w4.y = sigmf(w0c4.y + g_wr.y) * E;                                    \
        w4.z = sigmf(w0c4.z + g_wr.z) * E;                                    \
        w4.w = sigmf(w0c4.w + g_wr.w) * E;                                    \
        float4 v4;                                                            \
        v4.x = g_vr.x + (g_vf.x - g_vr.x) * sigmf(v0c4.x + g_vs.x);           \
        v4.y = g_vr.y + (g_vf.y - g_vr.y) * sigmf(v0c4.y + g_vs.y);           \
        v4.z = g_vr.z + (g_vf.z - g_vr.z) * sigmf(v0c4.z + g_vs.z);           \
        v4.w = g_vr.w + (g_vf.w - g_vr.w) * sigmf(v0c4.w + g_vs.w);           \
        float4 a4;                                                            \
        a4.x = sigmf(a0c4.x + g_ap.x);                                        \
        a4.y = sigmf(a0c4.y + g_ap.y);                                        \
        a4.z = sigmf(a0c4.z + g_ap.z);                                        \
        a4.w = sigmf(a0c4.w + g_ap.w);                                        \
        float4 kk;                                                            \
        kk.x = g_kr.x * kkc4.x; kk.y = g_kr.y * kkc4.y;                       \
        kk.z = g_kr.z * kkc4.z; kk.w = g_kr.w * kkc4.w;                       \
        float ss = kk.x * kk.x + kk.y * kk.y + kk.z * kk.z + kk.w * kk.w;     \
        ss = rowsum16(ss);                                                    \
        float inv = 1.0f / fmaxf(sqrtf(ss), 1e-12f);                          \
        float4 ah4, bh4, kh4;                                                 \
        ah4.x = -kk.x * inv; bh4.x = kk.x * inv * a4.x;                       \
        ah4.y = -kk.y * inv; bh4.y = kk.y * inv * a4.y;                       \
        ah4.z = -kk.z * inv; bh4.z = kk.z * inv * a4.z;                       \
        ah4.w = -kk.w * inv; bh4.w = kk.w * inv * a4.w;                       \
        kh4.x = g_kr.x * (1.0f + (a4.x - 1.0f) * kac4.x);                     \
        kh4.y = g_kr.y * (1.0f + (a4.y - 1.0f) * kac4.y);                     \
        kh4.z = g_kr.z * (1.0f + (a4.z - 1.0f) * kac4.z);                     \
        kh4.w = g_kr.w * (1.0f + (a4.w - 1.0f) * kac4.w);                     \
        *(float4*)((BN) + 0 * 1024 + wofs) = g_r;                             \
        *(float4*)((BN) + 1 * 1024 + wofs) = w4;                              \
        *(float4*)((BN) + 2 * 1024 + wofs) = kh4;                             \
        *(float4*)((BN) + 3 * 1024 + wofs) = ah4;                             \
        *(float4*)((BN) + 4 * 1024 + wofs) = bh4;                             \
        *(float4*)((BN) + 5 * 1024 + wofs) = v4;                              \
        *(float4*)((BN) + 6 * 1024 + wofs) = g_g;                             \
    }

    LOADSTAGE((size_t)cbeg * 16 * Cn)
    PARK(&buf[0][0][0][0])
    asm volatile("s_waitcnt lgkmcnt(0)" ::: "memory");
    __builtin_amdgcn_s_barrier();

#define DECL2(S)                                                              \
    float4 S##a0, S##w0, S##k0, S##b0, S##r0, S##v0;                          \
    float4 S##a1, S##w1, S##k1, S##b1, S##r1, S##v1;
#define DSLOAD2(S, T)                                                         \
    S##a0 = *(const float4*)(bc + 3 * 1024 + (T) * 64 + c0);                  \
    S##w0 = *(const float4*)(bc + 1 * 1024 + (T) * 64 + c0);                  \
    S##k0 = *(const float4*)(bc + 2 * 1024 + (T) * 64 + c0);                  \
    S##b0 = *(const float4*)(bc + 4 * 1024 + (T) * 64 + c0);                  \
    S##r0 = *(const float4*)(bc + 0 * 1024 + (T) * 64 + c0);                  \
    S##v0 = *(const float4*)(bc + 5 * 1024 + (T) * 64 + row0);                \
    S##a1 = *(const float4*)(bc + 3 * 1024 + ((T) + 1) * 64 + c0);            \
    S##w1 = *(const float4*)(bc + 1 * 1024 + ((T) + 1) * 64 + c0);            \
    S##k1 = *(const float4*)(bc + 2 * 1024 + ((T) + 1) * 64 + c0);            \
    S##b1 = *(const float4*)(bc + 4 * 1024 + ((T) + 1) * 64 + c0);            \
    S##r1 = *(const float4*)(bc + 0 * 1024 + ((T) + 1) * 64 + c0);            \
    S##v1 = *(const float4*)(bc + 5 * 1024 + ((T) + 1) * 64 + row0);
#define STEP(AV, WV, KV, BV, RV, VV, T)                                       \
    {                                                                         \
        float sp0 = s[0][0] * AV.x + s[0][1] * AV.y + s[0][2] * AV.z + s[0][3] * AV.w; \
        float sp1 = s[1][0] * AV.x + s[1][1] * AV.y + s[1][2] * AV.z + s[1][3] * AV.w; \
        float sp2 = s[2][0] * AV.x + s[2][1] * AV.y + s[2][2] * AV.z + s[2][3] * AV.w; \
        float sp3 = s[3][0] * AV.x + s[3][1] * AV.y + s[3][2] * AV.z + s[3][3] * AV.w; \
        sp0 = rowsum16(sp0);                                                  \
        sp1 = rowsum16(sp1);                                                  \
        sp2 = rowsum16(sp2);                                                  \
        sp3 = rowsum16(sp3);                                                  \
        float sa[4] = {sp0, sp1, sp2, sp3};                                   \
        float vr[4] = {VV.x, VV.y, VV.z, VV.w};                               \
        float op[4];                                                          \
        _Pragma("unroll")                                                     \
        for (int r = 0; r < 4; ++r) {                                         \
            s[r][0] = s[r][0] * WV.x + sa[r] * BV.x + vr[r] * KV.x;           \
            float o = s[r][0] * RV.x;                                         \
            s[r][1] = s[r][1] * WV.y + sa[r] * BV.y + vr[r] * KV.y;           \
            o += s[r][1] * RV.y;                                              \
            s[r][2] = s[r][2] * WV.z + sa[r] * BV.z + vr[r] * KV.z;           \
            o += s[r][2] * RV.z;                                              \
            s[r][3] = s[r][3] * WV.w + sa[r] * BV.w + vr[r] * KV.w;           \
            o += s[r][3] * RV.w;                                              \
            op[r] = rowsum16(o);                                              \
        }                                                                     \
        if (cg == 0)                                                          \
            *(float4*)&outL[T][row0] = make_float4(op[0], op[1], op[2], op[3]); \
    }

    DECL2(A) DECL2(B)

    int cur = 0;
    for (int c = cbeg; c < cendc; ++c) {
        const float* bc = &buf[cur][0][0][0];
        {
            int cnxt = (c + 1 < cendc) ? c + 1 : c;
            LOADSTAGE((size_t)cnxt * 16 * Cn)
        }

        DSLOAD2(A, 0)
#pragma unroll
        for (int it = 0; it < 4; ++it) {
            DSLOAD2(B, 4 * it + 2)
            STEP(Aa0, Aw0, Ak0, Ab0, Ar0, Av0, 4 * it + 0)
            STEP(Aa1, Aw1, Ak1, Ab1, Ar1, Av1, 4 * it + 1)
            if (it < 3) { DSLOAD2(A, 4 * it + 4) }
            STEP(Ba0, Bw0, Bk0, Bb0, Br0, Bv0, 4 * it + 2)
            STEP(Ba1, Bw1, Bk1, Bb1, Br1, Bv1, 4 * it + 3)
        }

        PARK(&buf[cur ^ 1][0][0][0])
        asm volatile("s_waitcnt lgkmcnt(0)" ::: "memory");
        __builtin_amdgcn_s_barrier();

        if (c >= coutc) {
            float4 o4 = *(const float4*)&outL[sstep][4 * sseg];
            float4 r4 = *(const float4*)(bc + 0 * 1024 + sstep * 64 + 4 * sseg);
            float4 k4 = *(const float4*)(bc + 2 * 1024 + sstep * 64 + 4 * sseg);
            float4 v4 = *(const float4*)(bc + 5 * 1024 + sstep * 64 + 4 * sseg);
            float4 gg4 = *(const float4*)(bc + 6 * 1024 + sstep * 64 + 4 * sseg);
            float m1 = o4.x + o4.y + o4.z + o4.w;
            float m2 = o4.x * o4.x + o4.y * o4.y + o4.z * o4.z + o4.w * o4.w;
            float bd = r4.x * k4.x * rk4.x + r4.y * k4.y * rk4.y +
                       r4.z * k4.z * rk4.z + r4.w * k4.w * rk4.w;
            m1 = rowsum16(m1);
            m2 = rowsum16(m2);
            bd = rowsum16(bd);
            float mean = m1 * (1.f / 64.f);
            float var = m2 * (1.f / 64.f) - mean * mean;
            float is = rsqrtf(var + 0.00064f);
            float xo0 = ((o4.x - mean) * is * lg4.x + lb4.x + bd * v4.x) * gg4.x;
            float xo1 = ((o4.y - mean) * is * lg4.y + lb4.y + bd * v4.y) * gg4.y;
            float xo2 = ((o4.z - mean) * is * lg4.z + lb4.z + bd * v4.z) * gg4.z;
            float xo3 = ((o4.w - mean) * is * lg4.w + lb4.w + bd * v4.w) * gg4.w;
            ushort h0 = f2bf(xo0), h1 = f2bf(xo1), h2 = f2bf(xo2), h3 = f2bf(xo3);
            ushort l0 = f2bf(xo0 - bf2f(h0)), l1 = f2bf(xo1 - bf2f(h1));
            ushort l2 = f2bf(xo2 - bf2f(h2)), l3 = f2bf(xo3 - bf2f(h3));
            size_t gt = (size_t)c * 16 + sstep;
            size_t eo = base + gt * Cn + 4 * sseg;
            *(ushort4*)(xsp + eo) = make_ushort4(h0, h1, h2, h3);
            *(ushort4*)(xsp + MCc + eo) = make_ushort4(l0, l1, l2, l3);
        }
        __builtin_amdgcn_s_barrier();
        cur ^= 1;
    }
#undef STEP
#undef DSLOAD2
#undef DECL2
#undef PARK
#undef LOADSTAGE
}

// ---------------------------------------------------------------------------
extern "C" void kernel_launch(void* const* d_in, const int* in_sizes, int n_in,
                              void* d_out, int out_size, void* d_ws, size_t ws_size,
                              hipStream_t stream)
{
    const float* x       = (const float*)d_in[0];
    const float* v_first = (const float*)d_in[1];
    const float* x_r     = (const float*)d_in[2];
    const float* x_w     = (const float*)d_in[3];
    const float* x_k     = (const float*)d_in[4];
    const float* x_v     = (const float*)d_in[5];
    const float* x_a     = (const float*)d_in[6];
    const float* x_g     = (const float*)d_in[7];
    const float* w0      = (const float*)d_in[8];
    const float* w1      = (const float*)d_in[9];
    const float* w2      = (const float*)d_in[10];
    const float* a0      = (const float*)d_in[11];
    const float* a1      = (const float*)d_in[12];
    const float* a2      = (const float*)d_in[13];
    const float* v0c     = (const float*)d_in[14];
    const float* v1      = (const float*)d_in[15];
    const float* v2      = (const float*)d_in[16];
    const float* g1w     = (const float*)d_in[17];
    const float* g2w     = (const float*)d_in[18];
    const float* k_k     = (const float*)d_in[19];
    const float* k_a     = (const float*)d_in[20];
    const float* r_k     = (const float*)d_in[21];
    const float* Wr      = (const float*)d_in[22];
    const float* Wk      = (const float*)d_in[23];
    const float* Wv      = (const float*)d_in[24];
    const float* Wo      = (const float*)d_in[25];
    const float* ln_g    = (const float*)d_in[26];
    const float* ln_b    = (const float*)d_in[27];
    float* out = (float*)d_out;

    float* ws = (float*)d_ws;
    float* B0 = ws + 0 * MCc;  // xr split pair -> wraw f32
    float* B1 = ws + 1 * MCc;  // xw split pair -> vsigp f32
    float* B2 = ws + 2 * MCc;  // xk split pair -> apre f32
    float* B3 = ws + 3 * MCc;  // scratch: hid split + arena + Wk/Wv splits
    float* B4 = ws + 4 * MCc;  // xa split pair -> xog split pair (scan out)
    float* B5 = ws + 5 * MCc;  // xg split pair -> g f32
    float* B6 = ws + 6 * MCc;  // r f32
    float* B7 = ws + 7 * MCc;  // k raw f32
    float* B8 = ws + 8 * MCc;  // v raw f32
    float* hid = ws + 9 * MCc; // [Mn,288] f32; also Wr/Wo split scratch

    ushort* XRsp = (ushort*)B0;
    ushort* XWsp = (ushort*)B1;
    ushort* XKsp = (ushort*)B2;
    ushort* XVsp = (ushort*)out;  // d_out scratch until stage 5
    ushort* XAsp = (ushort*)B4;
    ushort* XGsp = (ushort*)B5;
    ushort* S3 = (ushort*)B3;
    ushort* hidHi = S3;                     // 1,179,648
    ushort* hidLo = S3 + 1179648;           // 1,179,648
    ushort* arena = S3 + 2359296;           // 1,105,920
    ushort* WkS = S3 + 3465216;             // 1,843,200
    ushort* WvS = S3 + 5308416;             // 1,843,200 (ends 7,151,616 < 7,864,320)
    ushort* WrS = (ushort*)hid;             // 1,843,200 < 2,359,296 cap
    ushort* Whi = (ushort*)hid;             // Wo split later (hid dead)
    ushort* Wlo = Whi + (size_t)960 * 960;
    ushort* Xsp = (ushort*)B4;              // scan output split pair

    mix6_kernel<<<3840, 256, 0, stream>>>(x, x_r, x_w, x_k, x_v, x_a, x_g,
                                          XRsp, XWsp, XKsp, XVsp, XAsp, XGsp);
    wprep_kernel<<<dim3(30, 30, 8), 256, 0, stream>>>(w1, a1, v1, g1w,
                                                      w2, a2, v2, g2w, arena);
    // stage 1: all three weight splits in one dispatch, then merged GEMM
    convWT3_kernel<<<dim3(30, 30, 3), 256, 0, stream>>>(Wr, Wk, Wv,
                                                        WrS, WkS, WvS);
    gemm3_kernel<<<dim3(32, 15, 3), 256, 0, stream>>>(XRsp, XKsp, XVsp,
                                                      WrS, WkS, WvS,
                                                      B6, B7, B8);
    // stage 2: LoRA-down via MFMA (fused tanh/sigmoid)
    lora_down_kernel<<<dim3(32, 2, 4), 512, 0, stream>>>(XWsp, XAsp, XVsp, XGsp,
                                                         arena, hid);
    convN_kernel<<<1152, 256, 0, stream>>>(hid, hidHi, hidLo, Mn * 288 / 4);
    // stage 3: LoRA-up via MFMA -> B0=wraw, B2=apre, B1=vsigp, B5=g
    lora_up_kernel<<<dim3(32, 15, 4), 512, 0, stream>>>(hidHi, hidLo, arena,
                                                        B0, B2, B1, B5);
    // Wo split (hid f32 dead after convN)
    convWT_kernel<<<dim3(30, 30), 256, 0, stream>>>(Wo, Whi, Wlo);
    // stage 4: sequence-parallel scan, 8 segments (48-step warmup),
    // fused stage3e + norm/bonus/gate -> split pair in B4
    scan_kernel<<<480, 256, 0, stream>>>(B6, B0, B2, B1, B7, B8, v_first, B5,
                                         w0, a0, v0c, k_k, k_a,
                                         r_k, ln_g, ln_b, Xsp);
    // stage 5: output projection
    gemm1_kernel<<<dim3(32, 15), 256, 0, stream>>>(Xsp, Xsp + MCc, Whi, Wlo,
                                                   out, Cn);
}

// Round 23
// 305.219 us; speedup vs baseline: 1.0308x; 1.0308x over previous
//
#include <hip/hip_runtime.h>
#include <hip/hip_bf16.h>
#include <math.h>

#define Tn 1024
#define Cn 960
#define Hn 15
#define Nn 64
#define Mn 4096  // B*T

typedef short bf16x8 __attribute__((ext_vector_type(8)));
typedef float f32x4 __attribute__((ext_vector_type(4)));

#define MCc ((size_t)Mn * Cn)

__device__ __forceinline__ float sigmf(float x) { return 1.0f / (1.0f + __expf(-x)); }

// round-to-nearest-even f32 -> bf16 (as ushort)
__device__ __forceinline__ ushort f2bf(float x) {
    unsigned u = __float_as_uint(x);
    unsigned r = (u + 0x7FFFu + ((u >> 16) & 1u)) >> 16;
    return (ushort)r;
}
__device__ __forceinline__ float bf2f(ushort h) { return __uint_as_float(((unsigned)h) << 16); }

// full sum over the 16-lane DPP row via row_ror rotate-accumulate (all VALU).
__device__ __forceinline__ float rowsum16(float x) {
    x += __int_as_float(__builtin_amdgcn_update_dpp(0, __float_as_int(x), 0x121, 0xF, 0xF, true)); // ror:1
    x += __int_as_float(__builtin_amdgcn_update_dpp(0, __float_as_int(x), 0x122, 0xF, 0xF, true)); // ror:2
    x += __int_as_float(__builtin_amdgcn_update_dpp(0, __float_as_int(x), 0x124, 0xF, 0xF, true)); // ror:4
    x += __int_as_float(__builtin_amdgcn_update_dpp(0, __float_as_int(x), 0x128, 0xF, 0xF, true)); // ror:8
    return x;
}

// async global->LDS, 16B per lane; LDS dest = wave-uniform base + lane*16
#define GLOAD16(GPTR, LPTR)                                                   \
    __builtin_amdgcn_global_load_lds(                                         \
        (const __attribute__((address_space(1))) unsigned*)(GPTR),            \
        (__attribute__((address_space(3))) unsigned*)(LPTR), 16, 0, 0)

// ---------------------------------------------------------------------------
// token-shift + 6 mixes; ALL six emitted as split-bf16 pairs (hi @p, lo @p+MC)
// ---------------------------------------------------------------------------
__global__ __launch_bounds__(256) void mix6_kernel(
    const float* __restrict__ x,
    const float* __restrict__ mr, const float* __restrict__ mw, const float* __restrict__ mk,
    const float* __restrict__ mv, const float* __restrict__ ma, const float* __restrict__ mg,
    ushort* __restrict__ r_sp, ushort* __restrict__ w_sp, ushort* __restrict__ k_sp,
    ushort* __restrict__ v_sp, ushort* __restrict__ a_sp, ushort* __restrict__ g_sp)
{
    int idx = blockIdx.x * 256 + threadIdx.x;  // float4 index
    int e = idx * 4;
    if (e >= Mn * Cn) return;
    int m = e / Cn;
    int c = e - m * Cn;
    int t = m & (Tn - 1);
    float4 xv = *(const float4*)(x + e);
    float4 xp = make_float4(0.f, 0.f, 0.f, 0.f);
    if (t > 0) xp = *(const float4*)(x + e - Cn);
    float4 dx = make_float4(xp.x - xv.x, xp.y - xv.y, xp.z - xv.z, xp.w - xv.w);
#define MIXSPLIT(MIXP, P)                                                     \
    {                                                                         \
        float4 mm = *(const float4*)(MIXP + c);                               \
        float4 O = make_float4(xv.x + dx.x * mm.x, xv.y + dx.y * mm.y,        \
                               xv.z + dx.z * mm.z, xv.w + dx.w * mm.w);       \
        ushort h0 = f2bf(O.x), h1 = f2bf(O.y), h2 = f2bf(O.z), h3 = f2bf(O.w);\
        ushort l0 = f2bf(O.x - bf2f(h0)), l1 = f2bf(O.y - bf2f(h1));          \
        ushort l2 = f2bf(O.z - bf2f(h2)), l3 = f2bf(O.w - bf2f(h3));          \
        *(ushort4*)(P + e) = make_ushort4(h0, h1, h2, h3);                    \
        *(ushort4*)(P + MCc + e) = make_ushort4(l0, l1, l2, l3);              \
    }
    MIXSPLIT(mr, r_sp)
    MIXSPLIT(mw, w_sp)
    MIXSPLIT(mk, k_sp)
    MIXSPLIT(mv, v_sp)
    MIXSPLIT(ma, a_sp)
    MIXSPLIT(mg, g_sp)
#undef MIXSPLIT
}

// ---------------------------------------------------------------------------
// transpose + split-convert weight [960][960] -> [N][K] hi/lo (single)
// ---------------------------------------------------------------------------
__global__ __launch_bounds__(256) void convWT_kernel(
    const float* __restrict__ W, ushort* __restrict__ Thi, ushort* __restrict__ Tlo)
{
    __shared__ float tile[32][33];
    int k0 = blockIdx.x * 32, n0 = blockIdx.y * 32;
    int tx = threadIdx.x & 31, ty = threadIdx.x >> 5;  // 32 x 8
#pragma unroll
    for (int i = 0; i < 4; ++i)
        tile[ty + 8 * i][tx] = W[(size_t)(k0 + ty + 8 * i) * 960 + n0 + tx];
    __syncthreads();
#pragma unroll
    for (int i = 0; i < 4; ++i) {
        float x = tile[tx][ty + 8 * i];
        ushort h = f2bf(x);
        ushort l = f2bf(x - bf2f(h));
        size_t o = (size_t)(n0 + ty + 8 * i) * 960 + k0 + tx;
        Thi[o] = h;
        Tlo[o] = l;
    }
}

// merged z=3: Wr->S0, Wk->S1, Wv->S2
__global__ __launch_bounds__(256) void convWT3_kernel(
    const float* __restrict__ Wr, const float* __restrict__ Wk,
    const float* __restrict__ Wv,
    ushort* __restrict__ S0, ushort* __restrict__ S1, ushort* __restrict__ S2)
{
    __shared__ float tile[32][33];
    int z = blockIdx.z;
    const float* W = (z == 0) ? Wr : (z == 1) ? Wk : Wv;
    ushort* Thi = (z == 0) ? S0 : (z == 1) ? S1 : S2;
    ushort* Tlo = Thi + (size_t)960 * 960;
    int k0 = blockIdx.x * 32, n0 = blockIdx.y * 32;
    int tx = threadIdx.x & 31, ty = threadIdx.x >> 5;
#pragma unroll
    for (int i = 0; i < 4; ++i)
        tile[ty + 8 * i][tx] = W[(size_t)(k0 + ty + 8 * i) * 960 + n0 + tx];
    __syncthreads();
#pragma unroll
    for (int i = 0; i < 4; ++i) {
        float x = tile[tx][ty + 8 * i];
        ushort h = f2bf(x);
        ushort l = f2bf(x - bf2f(h));
        size_t o = (size_t)(n0 + ty + 8 * i) * 960 + k0 + tx;
        Thi[o] = h;
        Tlo[o] = l;
    }
}

// ---------------------------------------------------------------------------
// LoRA weight prep
// ---------------------------------------------------------------------------
__global__ __launch_bounds__(256) void wprep_kernel(
    const float* __restrict__ w1, const float* __restrict__ a1,
    const float* __restrict__ v1, const float* __restrict__ g1,
    const float* __restrict__ w2, const float* __restrict__ a2,
    const float* __restrict__ v2, const float* __restrict__ g2,
    ushort* __restrict__ arena)
{
    __shared__ float tile[32][33];
    int z = blockIdx.z;
    const float* src;
    int K, N;
    size_t off;
    switch (z) {
        case 0: src = w1; K = 960; N = 64;  off = 0;      break;
        case 1: src = a1; K = 960; N = 64;  off = 122880; break;
        case 2: src = v1; K = 960; N = 32;  off = 245760; break;
        case 3: src = g1; K = 960; N = 128; off = 307200; break;
        case 4: src = w2; K = 64;  N = 960; off = 552960; break;
        case 5: src = a2; K = 64;  N = 960; off = 675840; break;
        case 6: src = v2; K = 32;  N = 960; off = 798720; break;
        default: src = g2; K = 128; N = 960; off = 860160; break;
    }
    int k0 = blockIdx.x * 32, n0 = blockIdx.y * 32;
    if (k0 >= K || n0 >= N) return;
    int tx = threadIdx.x & 31, ty = threadIdx.x >> 5;
#pragma unroll
    for (int i = 0; i < 4; ++i)
        tile[ty + 8 * i][tx] = src[(size_t)(k0 + ty + 8 * i) * N + n0 + tx];
    __syncthreads();
    ushort* Thi = arena + off;
    ushort* Tlo = arena + off + (size_t)K * N;
#pragma unroll
    for (int i = 0; i < 4; ++i) {
        float x = tile[tx][ty + 8 * i];
        ushort h = f2bf(x);
        ushort l = f2bf(x - bf2f(h));
        size_t o = (size_t)(n0 + ty + 8 * i) * K + k0 + tx;
        Thi[o] = h;
        Tlo[o] = l;
    }
}

// ---------------------------------------------------------------------------
// split-convert arbitrary f32 array -> hi/lo bf16
// ---------------------------------------------------------------------------
__global__ __launch_bounds__(256) void convN_kernel(
    const float* __restrict__ X, ushort* __restrict__ hi, ushort* __restrict__ lo, int n4)
{
    int idx = blockIdx.x * 256 + threadIdx.x;
    if (idx >= n4) return;
    int e = idx * 4;
    float4 x = *(const float4*)(X + e);
    ushort h0 = f2bf(x.x), h1 = f2bf(x.y), h2 = f2bf(x.z), h3 = f2bf(x.w);
    ushort l0 = f2bf(x.x - bf2f(h0)), l1 = f2bf(x.y - bf2f(h1));
    ushort l2 = f2bf(x.z - bf2f(h2)), l3 = f2bf(x.w - bf2f(h3));
    *(ushort4*)(hi + e) = make_ushort4(h0, h1, h2, h3);
    *(ushort4*)(lo + e) = make_ushort4(l0, l1, l2, l3);
}

// ---------------------------------------------------------------------------
// split-bf16 MFMA GEMM core, 256 threads / 4 waves, BM=128 BN=64 BK=32.
// R19/R20 PROVEN version: global_load_lds staging, XOR-swizzled layout,
// 2-buffer (48KB <= 64KB static-LDS limit; the 3-buffer 72KB ring FAILED
// TO LAUNCH in R21/R22 — 64KB per-workgroup cap), vmcnt(0)+barrier/k-step.
// ---------------------------------------------------------------------------
__device__ __forceinline__ void gemm_core(
    const ushort* __restrict__ Ahi, const ushort* __restrict__ Alo,
    const ushort* __restrict__ Bhi, const ushort* __restrict__ Blo,
    float* __restrict__ C, int ldc, int bm, int bn)
{
    __shared__ __align__(16) ushort sA[2][2][128][32];  // 32768 B
    __shared__ __align__(16) ushort sB[2][2][64][32];   // 16384 B
    const int K = 960;
    int t = threadIdx.x;
    int w = t >> 6, l = t & 63;
    int lr = l & 15, lk = l >> 4;
    int lks = lk ^ ((lr >> 1) & 3);   // swizzled read chunk

    int srow = l >> 2;
    int skc = ((l & 3) ^ ((l >> 3) & 3)) * 8;
    const ushort* gA0h = Ahi + (size_t)(bm + 32 * w + srow) * K + skc;
    const ushort* gA1h = Ahi + (size_t)(bm + 32 * w + 16 + srow) * K + skc;
    const ushort* gA0l = Alo + (size_t)(bm + 32 * w + srow) * K + skc;
    const ushort* gA1l = Alo + (size_t)(bm + 32 * w + 16 + srow) * K + skc;
    const ushort* gBh = Bhi + (size_t)(bn + 16 * w + srow) * K + skc;
    const ushort* gBl = Blo + (size_t)(bn + 16 * w + srow) * K + skc;

    f32x4 acc[2][4];
#pragma unroll
    for (int i = 0; i < 2; ++i)
#pragma unroll
        for (int j = 0; j < 4; ++j)
#pragma unroll
            for (int e = 0; e < 4; ++e) acc[i][j][e] = 0.f;

#define STAGE(BUF, KOFF)                                                      \
    {                                                                         \
        GLOAD16(gA0h + (KOFF), &sA[BUF][0][32 * w][0]);                       \
        GLOAD16(gA1h + (KOFF), &sA[BUF][0][32 * w + 16][0]);                  \
        GLOAD16(gA0l + (KOFF), &sA[BUF][1][32 * w][0]);                       \
        GLOAD16(gA1l + (KOFF), &sA[BUF][1][32 * w + 16][0]);                  \
        GLOAD16(gBh + (KOFF), &sB[BUF][0][16 * w][0]);                        \
        GLOAD16(gBl + (KOFF), &sB[BUF][1][16 * w][0]);                        \
    }
#define COMPUTEK(BUF)                                                         \
    {                                                                         \
        bf16x8 ah[2], al[2], bh[4], bl[4];                                    \
        _Pragma("unroll")                                                     \
        for (int i = 0; i < 2; ++i) {                                         \
            ah[i] = *(const bf16x8*)&sA[BUF][0][32 * w + 16 * i + lr][lks * 8];\
            al[i] = *(const bf16x8*)&sA[BUF][1][32 * w + 16 * i + lr][lks * 8];\
        }                                                                     \
        _Pragma("unroll")                                                     \
        for (int j = 0; j < 4; ++j) {                                         \
            bh[j] = *(const bf16x8*)&sB[BUF][0][16 * j + lr][lks * 8];        \
            bl[j] = *(const bf16x8*)&sB[BUF][1][16 * j + lr][lks * 8];        \
        }                                                                     \
        _Pragma("unroll")                                                     \
        for (int i = 0; i < 2; ++i)                                           \
            _Pragma("unroll")                                                 \
            for (int j = 0; j < 4; ++j) {                                     \
                acc[i][j] = __builtin_amdgcn_mfma_f32_16x16x32_bf16(          \
                    ah[i], bh[j], acc[i][j], 0, 0, 0);                        \
                acc[i][j] = __builtin_amdgcn_mfma_f32_16x16x32_bf16(          \
                    ah[i], bl[j], acc[i][j], 0, 0, 0);                        \
                acc[i][j] = __builtin_amdgcn_mfma_f32_16x16x32_bf16(          \
                    al[i], bh[j], acc[i][j], 0, 0, 0);                        \
            }                                                                 \
    }

    STAGE(0, 0)
    asm volatile("s_waitcnt vmcnt(0)" ::: "memory");
    __builtin_amdgcn_s_barrier();

    int cur = 0;
    for (int ks = 0; ks < 30; ++ks) {
        if (ks + 1 < 30) STAGE(cur ^ 1, (ks + 1) * 32)
        COMPUTEK(cur)
        asm volatile("s_waitcnt vmcnt(0) lgkmcnt(0)" ::: "memory");
        __builtin_amdgcn_s_barrier();
        cur ^= 1;
    }

#pragma unroll
    for (int i = 0; i < 2; ++i)
#pragma unroll
        for (int j = 0; j < 4; ++j)
#pragma unroll
            for (int jr = 0; jr < 4; ++jr) {
                int row = bm + 32 * w + 16 * i + lk * 4 + jr;
                int col = bn + 16 * j + lr;
                C[(size_t)row * ldc + col] = acc[i][j][jr];
            }
#undef COMPUTEK
#undef STAGE
}

// merged stage-1: z=0 r, z=1 k, z=2 v
__global__ __launch_bounds__(256) void gemm3_kernel(
    const ushort* __restrict__ XR, const ushort* __restrict__ XK,
    const ushort* __restrict__ XV,
    const ushort* __restrict__ WrS, const ushort* __restrict__ WkS,
    const ushort* __restrict__ WvS,
    float* __restrict__ oR, float* __restrict__ oK, float* __restrict__ oV)
{
    int z = blockIdx.z;
    const ushort* A = (z == 0) ? XR : (z == 1) ? XK : XV;
    const ushort* W = (z == 0) ? WrS : (z == 1) ? WkS : WvS;
    float* C = (z == 0) ? oR : (z == 1) ? oK : oV;
    gemm_core(A, A + MCc, W, W + (size_t)960 * 960, C, Cn,
              blockIdx.x * 128, blockIdx.y * 64);
}

__global__ __launch_bounds__(256) void gemm1_kernel(
    const ushort* __restrict__ Ahi, const ushort* __restrict__ Alo,
    const ushort* __restrict__ Bhi, const ushort* __restrict__ Blo,
    float* __restrict__ C, int ldc)
{
    gemm_core(Ahi, Alo, Bhi, Blo, C, ldc, blockIdx.x * 128, blockIdx.y * 64);
}

// ---------------------------------------------------------------------------
// generic split-bf16 MFMA core for LoRA (512 threads) — unchanged
// ---------------------------------------------------------------------------
__device__ __forceinline__ void lora_core(
    const ushort* __restrict__ Ahi, const ushort* __restrict__ Alo, int lda,
    const ushort* __restrict__ Bhi, const ushort* __restrict__ Blo,
    float* __restrict__ C, int ldc, int Nvalid, int K, int act, int bn)
{
    __shared__ __align__(16) ushort sA[2][2][128][40];
    __shared__ __align__(16) ushort sB[2][2][64][40];
    int bm = blockIdx.x * 128;
    int t = threadIdx.x;
    int w = t >> 6, l = t & 63;
    int lr = l & 15, lk = l >> 4;

    int ar = t >> 2, aseg = t & 3;
    int brr = t >> 2;
    int bhl = brr >> 6, brow = brr & 63, bseg = t & 3;
    const ushort* gAh = Ahi + (size_t)(bm + ar) * lda + aseg * 8;
    const ushort* gAl = Alo + (size_t)(bm + ar) * lda + aseg * 8;
    const ushort* gB = (bhl ? Blo : Bhi) + (size_t)(bn + brow) * K + bseg * 8;

    f32x4 acc[4];
#pragma unroll
    for (int j = 0; j < 4; ++j)
#pragma unroll
        for (int e = 0; e < 4; ++e) acc[j][e] = 0.f;

    float4 rhP, rlP, rbP, rhQ, rlQ, rbQ;
#define LLOADP(KOFF)                                                          \
    {                                                                         \
        rhP = *(const float4*)(gAh + (KOFF));                                 \
        rlP = *(const float4*)(gAl + (KOFF));                                 \
        rbP = *(const float4*)(gB + (KOFF));                                  \
    }
#define LLOADQ(KOFF)                                                          \
    {                                                                         \
        rhQ = *(const float4*)(gAh + (KOFF));                                 \
        rlQ = *(const float4*)(gAl + (KOFF));                                 \
        rbQ = *(const float4*)(gB + (KOFF));                                  \
    }
#define LWRITEP(BUF)                                                          \
    {                                                                         \
        *(float4*)&sA[BUF][0][ar][aseg * 8] = rhP;                            \
        *(float4*)&sA[BUF][1][ar][aseg * 8] = rlP;                            \
        *(float4*)&sB[BUF][bhl][brow][bseg * 8] = rbP;                        \
    }
#define LWRITEQ(BUF)                                                          \
    {                                                                         \
        *(float4*)&sA[BUF][0][ar][aseg * 8] = rhQ;                            \
        *(float4*)&sA[BUF][1][ar][aseg * 8] = rlQ;                            \
        *(float4*)&sB[BUF][bhl][brow][bseg * 8] = rbQ;                        \
    }
#define LCOMPUTE(BUF)                                                         \
    {                                                                         \
        bf16x8 ah, al, bh[4], bl[4];                                          \
        ah = *(const bf16x8*)&sA[BUF][0][16 * w + lr][lk * 8];                \
        al = *(const bf16x8*)&sA[BUF][1][16 * w + lr][lk * 8];                \
        _Pragma("unroll")                                                     \
        for (int j = 0; j < 4; ++j) {                                         \
            bh[j] = *(const bf16x8*)&sB[BUF][0][16 * j + lr][lk * 8];         \
            bl[j] = *(const bf16x8*)&sB[BUF][1][16 * j + lr][lk * 8];         \
        }                                                                     \
        _Pragma("unroll")                                                     \
        for (int j = 0; j < 4; ++j) {                                         \
            acc[j] = __builtin_amdgcn_mfma_f32_16x16x32_bf16(ah, bh[j], acc[j], 0, 0, 0); \
            acc[j] = __builtin_amdgcn_mfma_f32_16x16x32_bf16(ah, bl[j], acc[j], 0, 0, 0); \
            acc[j] = __builtin_amdgcn_mfma_f32_16x16x32_bf16(al, bh[j], acc[j], 0, 0, 0); \
        }                                                                     \
    }

    int nk = K >> 5;
    LLOADP(0)
    LWRITEP(0)
    if (nk > 1) LLOADQ(32)
    asm volatile("s_waitcnt lgkmcnt(0)" ::: "memory");
    __builtin_amdgcn_s_barrier();

    int cur = 0;
    for (int ks = 0; ks < nk; ++ks) {
        int k2 = (ks + 2 < nk ? ks + 2 : nk - 1) * 32;
        if (!(ks & 1)) { LLOADP(k2) } else { LLOADQ(k2) }
        LCOMPUTE(cur)
        if (ks + 1 < nk) {
            if (!(ks & 1)) { LWRITEQ(cur ^ 1) } else { LWRITEP(cur ^ 1) }
            asm volatile("s_waitcnt lgkmcnt(0)" ::: "memory");
            __builtin_amdgcn_s_barrier();
        }
        cur ^= 1;
    }

#pragma unroll
    for (int j = 0; j < 4; ++j)
#pragma unroll
        for (int jr = 0; jr < 4; ++jr) {
            int row = bm + 16 * w + lk * 4 + jr;
            int col = bn + 16 * j + lr;
            if (col < Nvalid) {
                float v = acc[j][jr];
                if (act == 1) v = tanhf(v);
                else if (act == 2) v = sigmf(v);
                C[(size_t)row * ldc + col] = v;
            }
        }
#undef LCOMPUTE
#undef LWRITEP
#undef LWRITEQ
#undef LLOADP
#undef LLOADQ
}

// LoRA-down MFMA: grid (32, 2, 4)
__global__ __launch_bounds__(512) void lora_down_kernel(
    const ushort* __restrict__ xw_sp, const ushort* __restrict__ xa_sp,
    const ushort* __restrict__ xv_sp, const ushort* __restrict__ xg_sp,
    const ushort* __restrict__ arena, float* __restrict__ hid)
{
    int z = blockIdx.z;
    int bn = blockIdx.y * 64;
    const ushort* A;
    size_t off;
    int N, act, coff;
    switch (z) {
        case 0: A = xw_sp; off = 0;      N = 64;  act = 1; coff = 0;   break;
        case 1: A = xa_sp; off = 122880; N = 64;  act = 0; coff = 64;  break;
        case 2: A = xv_sp; off = 245760; N = 32;  act = 0; coff = 128; break;
        default: A = xg_sp; off = 307200; N = 128; act = 2; coff = 160; break;
    }
    if (bn >= N) return;
    lora_core(A, A + MCc, Cn, arena + off, arena + off + (size_t)960 * N,
              hid + coff, 288, N, 960, act, bn);
}

// LoRA-up MFMA: grid (32, 15, 4)
__global__ __launch_bounds__(512) void lora_up_kernel(
    const ushort* __restrict__ hidHi, const ushort* __restrict__ hidLo,
    const ushort* __restrict__ arena,
    float* __restrict__ oW, float* __restrict__ oA,
    float* __restrict__ oV, float* __restrict__ oG)
{
    int z = blockIdx.z;
    int bn = blockIdx.y * 64;
    size_t off;
    int K, aoff;
    float* C;
    switch (z) {
        case 0: off = 552960; K = 64;  aoff = 0;   C = oW; break;
        case 1: off = 675840; K = 64;  aoff = 64;  C = oA; break;
        case 2: off = 798720; K = 32;  aoff = 128; C = oV; break;
        default: off = 860160; K = 128; aoff = 160; C = oG; break;
    }
    lora_core(hidHi + aoff, hidLo + aoff, 288, arena + off,
              arena + off + (size_t)K * 960, C, Cn, Cn, K, 0, bn);
}

// ---------------------------------------------------------------------------
// SEQUENCE-PARALLEL chunked scan: 8 segments (480 blocks), 16-step chunks,
// 32-step warmup (single isolated change this round; 128/64/48 were all
// bit-exact; contraction <=0.6/step => <=7e-8 carried state over 32 steps).
// ---------------------------------------------------------------------------
__global__ __launch_bounds__(256, 2) void scan_kernel(
    const float* __restrict__ rP, const float* __restrict__ wrawP,
    const float* __restrict__ apreP, const float* __restrict__ vsigP,
    const float* __restrict__ krawP, const float* __restrict__ vrawP,
    const float* __restrict__ vfirstP, const float* __restrict__ gP,
    const float* __restrict__ w0, const float* __restrict__ a0,
    const float* __restrict__ v0c, const float* __restrict__ kkc,
    const float* __restrict__ kac, const float* __restrict__ r_k,
    const float* __restrict__ ln_g, const float* __restrict__ ln_b,
    ushort* __restrict__ xsp)
{
    __shared__ float buf[2][7][16][64];  // 57344 B
    __shared__ float outL[16][64];       // 4096 B
    int tid = threadIdx.x;
    int q = tid >> 6, l = tid & 63;
    int blk = blockIdx.x;
    int bh = blk >> 3, seg = blk & 7;
    int bb = bh / Hn, h = bh - bb * Hn;
    size_t base = (size_t)bb * Tn * Cn + h * 64;
    int rg = l >> 4, cg = l & 15;
    int row0 = 16 * q + 4 * rg;
    int c0 = 4 * cg;

    int sstep = tid >> 4, sseg = tid & 15;
    size_t soff = base + (size_t)sstep * Cn + sseg * 4;
    int wofs = sstep * 64 + sseg * 4;
    int ccol = h * 64 + sseg * 4;

    int cbeg = (seg == 0) ? 0 : 8 * seg - 2;
    int cendc = 8 * seg + 8;
    int coutc = 8 * seg;

    float4 w0c4 = *(const float4*)(w0 + ccol);
    float4 a0c4 = *(const float4*)(a0 + ccol);
    float4 v0c4 = *(const float4*)(v0c + ccol);
    float4 kkc4 = *(const float4*)(kkc + ccol);
    float4 kac4 = *(const float4*)(kac + ccol);
    float4 rk4 = *(const float4*)(r_k + ccol);
    float4 lg4 = *(const float4*)(ln_g + ccol);
    float4 lb4 = *(const float4*)(ln_b + ccol);

    float s[4][4];
#pragma unroll
    for (int r = 0; r < 4; ++r)
#pragma unroll
        for (int c = 0; c < 4; ++c) s[r][c] = 0.f;

    float4 g_r, g_wr, g_vr, g_vf, g_vs, g_g, g_kr, g_ap;

#define LOADSTAGE(OFF)                                                        \
    g_r = *(const float4*)(rP + soff + (OFF));                                \
    g_wr = *(const float4*)(wrawP + soff + (OFF));                            \
    g_vr = *(const float4*)(vrawP + soff + (OFF));                            \
    g_vf = *(const float4*)(vfirstP + soff + (OFF));                          \
    g_vs = *(const float4*)(vsigP + soff + (OFF));                            \
    g_g = *(const float4*)(gP + soff + (OFF));                                \
    g_kr = *(const float4*)(krawP + soff + (OFF));                            \
    g_ap = *(const float4*)(apreP + soff + (OFF));

#define PARK(BN)                                                              \
    {                                                                         \
        const float E = 0.60653065971263342f;                                 \
        float4 w4;                                                            \
        w4.x = sigmf(w0c4.x + g_wr.x) * E;                                    \
        w4.y = sigmf(w0c4.y + g_wr.y) * E;                                    \
        w4.z = sigmf(w0c4.z + g_wr.z) * E;                                    \
        w4.w = sigmf(w0c4.w + g_wr.w) * E;                                    \
        float4 v4;                                                            \
        v4.x = g_vr.x + (g_vf.x - g_vr.x) * sigmf(v0c4.x + g_vs.x);           \
        v4.y = g_vr.y + (g_vf.y - g_vr.y) * sigmf(v0c4.y + g_vs.y);           \
        v4.z = g_vr.z + (g_vf.z - g_vr.z) * sigmf(v0c4.z + g_vs.z);           \
        v4.w = g_vr.w + (g_vf.w - g_vr.w) * sigmf(v0c4.w + g_vs.w);           \
        float4 a4;                                                            \
        a4.x = sigmf(a0c4.x + g_ap.x);                                        \
        a4.y = sigmf(a0c4.y + g_ap.y);                                        \
        a4.z = sigmf(a0c4.z + g_ap.z);                                        \
        a4.w = sigmf(a0c4.w + g_ap.w);                                        \
        float4 kk;                                                            \
        kk.x = g_kr.x * kkc4.x; kk.y = g_kr.y * kkc4.y;                       \
        kk.z = g_kr.z * kkc4.z; kk.w = g_kr.w * kkc4.w;                       \
        float ss = kk.x * kk.x + kk.y * kk.y + kk.z * kk.z + kk.w * kk.w;     \
        ss = rowsum16(ss);                                                    \
        float inv = 1.0f / fmaxf(sqrtf(ss), 1e-12f);                          \
        float4 ah4, bh4, kh4;                                                 \
        ah4.x = -kk.x * inv; bh4.x = kk.x * inv * a4.x;                       \
        ah4.y = -kk.y * inv; bh4.y = kk.y * inv * a4.y;                       \
        ah4.z = -kk.z * inv; bh4.z = kk.z * inv * a4.z;                       \
        ah4.w = -kk.w * inv; bh4.w = kk.w * inv * a4.w;                       \
        kh4.x = g_kr.x * (1.0f + (a4.x - 1.0f) * kac4.x);                     \
        kh4.y = g_kr.y * (1.0f + (a4.y - 1.0f) * kac4.y);                     \
        kh4.z = g_kr.z * (1.0f + (a4.z - 1.0f) * kac4.z);                     \
        kh4.w = g_kr.w * (1.0f + (a4.w - 1.0f) * kac4.w);                     \
        *(float4*)((BN) + 0 * 1024 + wofs) = g_r;                             \
        *(float4*)((BN) + 1 * 1024 + wofs) = w4;                              \
        *(float4*)((BN) + 2 * 1024 + wofs) = kh4;                             \
        *(float4*)((BN) + 3 * 1024 + wofs) = ah4;                             \
        *(float4*)((BN) + 4 * 1024 + wofs) = bh4;                             \
        *(float4*)((BN) + 5 * 1024 + wofs) = v4;                              \
        *(float4*)((BN) + 6 * 1024 + wofs) = g_g;                             \
    }

    LOADSTAGE((size_t)cbeg * 16 * Cn)
    PARK(&buf[0][0][0][0])
    asm volatile("s_waitcnt lgkmcnt(0)" ::: "memory");
    __builtin_amdgcn_s_barrier();

#define DECL2(S)                                                              \
    float4 S##a0, S##w0, S##k0, S##b0, S##r0, S##v0;                          \
    float4 S##a1, S##w1, S##k1, S##b1, S##r1, S##v1;
#define DSLOAD2(S, T)                                                         \
    S##a0 = *(const float4*)(bc + 3 * 1024 + (T) * 64 + c0);                  \
    S##w0 = *(const float4*)(bc + 1 * 1024 + (T) * 64 + c0);                  \
    S##k0 = *(const float4*)(bc + 2 * 1024 + (T) * 64 + c0);                  \
    S##b0 = *(const float4*)(bc + 4 * 1024 + (T) * 64 + c0);                  \
    S##r0 = *(const float4*)(bc + 0 * 1024 + (T) * 64 + c0);                  \
    S##v0 = *(const float4*)(bc + 5 * 1024 + (T) * 64 + row0);                \
    S##a1 = *(const float4*)(bc + 3 * 1024 + ((T) + 1) * 64 + c0);            \
    S##w1 = *(const float4*)(bc + 1 * 1024 + ((T) + 1) * 64 + c0);            \
    S##k1 = *(const float4*)(bc + 2 * 1024 + ((T) + 1) * 64 + c0);            \
    S##b1 = *(const float4*)(bc + 4 * 1024 + ((T) + 1) * 64 + c0);            \
    S##r1 = *(const float4*)(bc + 0 * 1024 + ((T) + 1) * 64 + c0);            \
    S##v1 = *(const float4*)(bc + 5 * 1024 + ((T) + 1) * 64 + row0);
#define STEP(AV, WV, KV, BV, RV, VV, T)                                       \
    {                                                                         \
        float sp0 = s[0][0] * AV.x + s[0][1] * AV.y + s[0][2] * AV.z + s[0][3] * AV.w; \
        float sp1 = s[1][0] * AV.x + s[1][1] * AV.y + s[1][2] * AV.z + s[1][3] * AV.w; \
        float sp2 = s[2][0] * AV.x + s[2][1] * AV.y + s[2][2] * AV.z + s[2][3] * AV.w; \
        float sp3 = s[3][0] * AV.x + s[3][1] * AV.y + s[3][2] * AV.z + s[3][3] * AV.w; \
        sp0 = rowsum16(sp0);                                                  \
        sp1 = rowsum16(sp1);                                                  \
        sp2 = rowsum16(sp2);                                                  \
        sp3 = rowsum16(sp3);                                                  \
        float sa[4] = {sp0, sp1, sp2, sp3};                                   \
        float vr[4] = {VV.x, VV.y, VV.z, VV.w};                               \
        float op[4];                                                          \
        _Pragma("unroll")                                                     \
        for (int r = 0; r < 4; ++r) {                                         \
            s[r][0] = s[r][0] * WV.x + sa[r] * BV.x + vr[r] * KV.x;           \
            float o = s[r][0] * RV.x;                                         \
            s[r][1] = s[r][1] * WV.y + sa[r] * BV.y + vr[r] * KV.y;           \
            o += s[r][1] * RV.y;                                              \
            s[r][2] = s[r][2] * WV.z + sa[r] * BV.z + vr[r] * KV.z;           \
            o += s[r][2] * RV.z;                                              \
            s[r][3] = s[r][3] * WV.w + sa[r] * BV.w + vr[r] * KV.w;           \
            o += s[r][3] * RV.w;                                              \
            op[r] = rowsum16(o);                                              \
        }                                                                     \
        if (cg == 0)                                                          \
            *(float4*)&outL[T][row0] = make_float4(op[0], op[1], op[2], op[3]); \
    }

    DECL2(A) DECL2(B)

    int cur = 0;
    for (int c = cbeg; c < cendc; ++c) {
        const float* bc = &buf[cur][0][0][0];
        {
            int cnxt = (c + 1 < cendc) ? c + 1 : c;
            LOADSTAGE((size_t)cnxt * 16 * Cn)
        }

        DSLOAD2(A, 0)
#pragma unroll
        for (int it = 0; it < 4; ++it) {
            DSLOAD2(B, 4 * it + 2)
            STEP(Aa0, Aw0, Ak0, Ab0, Ar0, Av0, 4 * it + 0)
            STEP(Aa1, Aw1, Ak1, Ab1, Ar1, Av1, 4 * it + 1)
            if (it < 3) { DSLOAD2(A, 4 * it + 4) }
            STEP(Ba0, Bw0, Bk0, Bb0, Br0, Bv0, 4 * it + 2)
            STEP(Ba1, Bw1, Bk1, Bb1, Br1, Bv1, 4 * it + 3)
        }

        PARK(&buf[cur ^ 1][0][0][0])
        asm volatile("s_waitcnt lgkmcnt(0)" ::: "memory");
        __builtin_amdgcn_s_barrier();

        if (c >= coutc) {
            float4 o4 = *(const float4*)&outL[sstep][4 * sseg];
            float4 r4 = *(const float4*)(bc + 0 * 1024 + sstep * 64 + 4 * sseg);
            float4 k4 = *(const float4*)(bc + 2 * 1024 + sstep * 64 + 4 * sseg);
            float4 v4 = *(const float4*)(bc + 5 * 1024 + sstep * 64 + 4 * sseg);
            float4 gg4 = *(const float4*)(bc + 6 * 1024 + sstep * 64 + 4 * sseg);
            float m1 = o4.x + o4.y + o4.z + o4.w;
            float m2 = o4.x * o4.x + o4.y * o4.y + o4.z * o4.z + o4.w * o4.w;
            float bd = r4.x * k4.x * rk4.x + r4.y * k4.y * rk4.y +
                       r4.z * k4.z * rk4.z + r4.w * k4.w * rk4.w;
            m1 = rowsum16(m1);
            m2 = rowsum16(m2);
            bd = rowsum16(bd);
            float mean = m1 * (1.f / 64.f);
            float var = m2 * (1.f / 64.f) - mean * mean;
            float is = rsqrtf(var + 0.00064f);
            float xo0 = ((o4.x - mean) * is * lg4.x + lb4.x + bd * v4.x) * gg4.x;
            float xo1 = ((o4.y - mean) * is * lg4.y + lb4.y + bd * v4.y) * gg4.y;
            float xo2 = ((o4.z - mean) * is * lg4.z + lb4.z + bd * v4.z) * gg4.z;
            float xo3 = ((o4.w - mean) * is * lg4.w + lb4.w + bd * v4.w) * gg4.w;
            ushort h0 = f2bf(xo0), h1 = f2bf(xo1), h2 = f2bf(xo2), h3 = f2bf(xo3);
            ushort l0 = f2bf(xo0 - bf2f(h0)), l1 = f2bf(xo1 - bf2f(h1));
            ushort l2 = f2bf(xo2 - bf2f(h2)), l3 = f2bf(xo3 - bf2f(h3));
            size_t gt = (size_t)c * 16 + sstep;
            size_t eo = base + gt * Cn + 4 * sseg;
            *(ushort4*)(xsp + eo) = make_ushort4(h0, h1, h2, h3);
            *(ushort4*)(xsp + MCc + eo) = make_ushort4(l0, l1, l2, l3);
        }
        __builtin_amdgcn_s_barrier();
        cur ^= 1;
    }
#undef STEP
#undef DSLOAD2
#undef DECL2
#undef PARK
#undef LOADSTAGE
}

// ---------------------------------------------------------------------------
extern "C" void kernel_launch(void* const* d_in, const int* in_sizes, int n_in,
                              void* d_out, int out_size, void* d_ws, size_t ws_size,
                              hipStream_t stream)
{
    const float* x       = (const float*)d_in[0];
    const float* v_first = (const float*)d_in[1];
    const float* x_r     = (const float*)d_in[2];
    const float* x_w     = (const float*)d_in[3];
    const float* x_k     = (const float*)d_in[4];
    const float* x_v     = (const float*)d_in[5];
    const float* x_a     = (const float*)d_in[6];
    const float* x_g     = (const float*)d_in[7];
    const float* w0      = (const float*)d_in[8];
    const float* w1      = (const float*)d_in[9];
    const float* w2      = (const float*)d_in[10];
    const float* a0      = (const float*)d_in[11];
    const float* a1      = (const float*)d_in[12];
    const float* a2      = (const float*)d_in[13];
    const float* v0c     = (const float*)d_in[14];
    const float* v1      = (const float*)d_in[15];
    const float* v2      = (const float*)d_in[16];
    const float* g1w     = (const float*)d_in[17];
    const float* g2w     = (const float*)d_in[18];
    const float* k_k     = (const float*)d_in[19];
    const float* k_a     = (const float*)d_in[20];
    const float* r_k     = (const float*)d_in[21];
    const float* Wr      = (const float*)d_in[22];
    const float* Wk      = (const float*)d_in[23];
    const float* Wv      = (const float*)d_in[24];
    const float* Wo      = (const float*)d_in[25];
    const float* ln_g    = (const float*)d_in[26];
    const float* ln_b    = (const float*)d_in[27];
    float* out = (float*)d_out;

    float* ws = (float*)d_ws;
    float* B0 = ws + 0 * MCc;  // xr split pair -> wraw f32
    float* B1 = ws + 1 * MCc;  // xw split pair -> vsigp f32
    float* B2 = ws + 2 * MCc;  // xk split pair -> apre f32
    float* B3 = ws + 3 * MCc;  // scratch: hid split + arena + Wk/Wv splits
    float* B4 = ws + 4 * MCc;  // xa split pair -> xog split pair (scan out)
    float* B5 = ws + 5 * MCc;  // xg split pair -> g f32
    float* B6 = ws + 6 * MCc;  // r f32
    float* B7 = ws + 7 * MCc;  // k raw f32
    float* B8 = ws + 8 * MCc;  // v raw f32
    float* hid = ws + 9 * MCc; // [Mn,288] f32; also Wr/Wo split scratch

    ushort* XRsp = (ushort*)B0;
    ushort* XWsp = (ushort*)B1;
    ushort* XKsp = (ushort*)B2;
    ushort* XVsp = (ushort*)out;  // d_out scratch until stage 5
    ushort* XAsp = (ushort*)B4;
    ushort* XGsp = (ushort*)B5;
    ushort* S3 = (ushort*)B3;
    ushort* hidHi = S3;                     // 1,179,648
    ushort* hidLo = S3 + 1179648;           // 1,179,648
    ushort* arena = S3 + 2359296;           // 1,105,920
    ushort* WkS = S3 + 3465216;             // 1,843,200
    ushort* WvS = S3 + 5308416;             // 1,843,200 (ends 7,151,616 < 7,864,320)
    ushort* WrS = (ushort*)hid;             // 1,843,200 < 2,359,296 cap
    ushort* Whi = (ushort*)hid;             // Wo split later (hid dead)
    ushort* Wlo = Whi + (size_t)960 * 960;
    ushort* Xsp = (ushort*)B4;              // scan output split pair

    mix6_kernel<<<3840, 256, 0, stream>>>(x, x_r, x_w, x_k, x_v, x_a, x_g,
                                          XRsp, XWsp, XKsp, XVsp, XAsp, XGsp);
    wprep_kernel<<<dim3(30, 30, 8), 256, 0, stream>>>(w1, a1, v1, g1w,
                                                      w2, a2, v2, g2w, arena);
    // stage 1: all three weight splits in one dispatch, then merged GEMM
    convWT3_kernel<<<dim3(30, 30, 3), 256, 0, stream>>>(Wr, Wk, Wv,
                                                        WrS, WkS, WvS);
    gemm3_kernel<<<dim3(32, 15, 3), 256, 0, stream>>>(XRsp, XKsp, XVsp,
                                                      WrS, WkS, WvS,
                                                      B6, B7, B8);
    // stage 2: LoRA-down via MFMA (fused tanh/sigmoid)
    lora_down_kernel<<<dim3(32, 2, 4), 512, 0, stream>>>(XWsp, XAsp, XVsp, XGsp,
                                                         arena, hid);
    convN_kernel<<<1152, 256, 0, stream>>>(hid, hidHi, hidLo, Mn * 288 / 4);
    // stage 3: LoRA-up via MFMA -> B0=wraw, B2=apre, B1=vsigp, B5=g
    lora_up_kernel<<<dim3(32, 15, 4), 512, 0, stream>>>(hidHi, hidLo, arena,
                                                        B0, B2, B1, B5);
    // Wo split (hid f32 dead after convN)
    convWT_kernel<<<dim3(30, 30), 256, 0, stream>>>(Wo, Whi, Wlo);
    // stage 4: sequence-parallel scan, 8 segments (32-step warmup),
    // fused stage3e + norm/bonus/gate -> split pair in B4
    scan_kernel<<<480, 256, 0, stream>>>(B6, B0, B2, B1, B7, B8, v_first, B5,
                                         w0, a0, v0c, k_k, k_a,
                                         r_k, ln_g, ln_b, Xsp);
    // stage 5: output projection
    gemm1_kernel<<<dim3(32, 15), 256, 0, stream>>>(Xsp, Xsp + MCc, Whi, Wlo,
                                                   out, Cn);
}

// Round 25
// 304.875 us; speedup vs baseline: 1.0319x; 1.0011x over previous
//
#include <hip/hip_runtime.h>
#include <hip/hip_bf16.h>
#include <math.h>

#define Tn 1024
#define Cn 960
#define Hn 15
#define Nn 64
#define Mn 4096  // B*T

typedef short bf16x8 __attribute__((ext_vector_type(8)));
typedef float f32x4 __attribute__((ext_vector_type(4)));

#define MCc ((size_t)Mn * Cn)

__device__ __forceinline__ float sigmf(float x) { return 1.0f / (1.0f + __expf(-x)); }

// round-to-nearest-even f32 -> bf16 (as ushort)
__device__ __forceinline__ ushort f2bf(float x) {
    unsigned u = __float_as_uint(x);
    unsigned r = (u + 0x7FFFu + ((u >> 16) & 1u)) >> 16;
    return (ushort)r;
}
__device__ __forceinline__ float bf2f(ushort h) { return __uint_as_float(((unsigned)h) << 16); }

// full sum over the 16-lane DPP row via row_ror rotate-accumulate (all VALU).
__device__ __forceinline__ float rowsum16(float x) {
    x += __int_as_float(__builtin_amdgcn_update_dpp(0, __float_as_int(x), 0x121, 0xF, 0xF, true)); // ror:1
    x += __int_as_float(__builtin_amdgcn_update_dpp(0, __float_as_int(x), 0x122, 0xF, 0xF, true)); // ror:2
    x += __int_as_float(__builtin_amdgcn_update_dpp(0, __float_as_int(x), 0x124, 0xF, 0xF, true)); // ror:4
    x += __int_as_float(__builtin_amdgcn_update_dpp(0, __float_as_int(x), 0x128, 0xF, 0xF, true)); // ror:8
    return x;
}

// async global->LDS, 16B per lane; LDS dest = wave-uniform base + lane*16
#define GLOAD16(GPTR, LPTR)                                                   \
    __builtin_amdgcn_global_load_lds(                                         \
        (const __attribute__((address_space(1))) unsigned*)(GPTR),            \
        (__attribute__((address_space(3))) unsigned*)(LPTR), 16, 0, 0)

// ---------------------------------------------------------------------------
// token-shift + 6 mixes; ALL six emitted as split-bf16 pairs (hi @p, lo @p+MC)
// ---------------------------------------------------------------------------
__global__ __launch_bounds__(256) void mix6_kernel(
    const float* __restrict__ x,
    const float* __restrict__ mr, const float* __restrict__ mw, const float* __restrict__ mk,
    const float* __restrict__ mv, const float* __restrict__ ma, const float* __restrict__ mg,
    ushort* __restrict__ r_sp, ushort* __restrict__ w_sp, ushort* __restrict__ k_sp,
    ushort* __restrict__ v_sp, ushort* __restrict__ a_sp, ushort* __restrict__ g_sp)
{
    int idx = blockIdx.x * 256 + threadIdx.x;  // float4 index
    int e = idx * 4;
    if (e >= Mn * Cn) return;
    int m = e / Cn;
    int c = e - m * Cn;
    int t = m & (Tn - 1);
    float4 xv = *(const float4*)(x + e);
    float4 xp = make_float4(0.f, 0.f, 0.f, 0.f);
    if (t > 0) xp = *(const float4*)(x + e - Cn);
    float4 dx = make_float4(xp.x - xv.x, xp.y - xv.y, xp.z - xv.z, xp.w - xv.w);
#define MIXSPLIT(MIXP, P)                                                     \
    {                                                                         \
        float4 mm = *(const float4*)(MIXP + c);                               \
        float4 O = make_float4(xv.x + dx.x * mm.x, xv.y + dx.y * mm.y,        \
                               xv.z + dx.z * mm.z, xv.w + dx.w * mm.w);       \
        ushort h0 = f2bf(O.x), h1 = f2bf(O.y), h2 = f2bf(O.z), h3 = f2bf(O.w);\
        ushort l0 = f2bf(O.x - bf2f(h0)), l1 = f2bf(O.y - bf2f(h1));          \
        ushort l2 = f2bf(O.z - bf2f(h2)), l3 = f2bf(O.w - bf2f(h3));          \
        *(ushort4*)(P + e) = make_ushort4(h0, h1, h2, h3);                    \
        *(ushort4*)(P + MCc + e) = make_ushort4(l0, l1, l2, l3);              \
    }
    MIXSPLIT(mr, r_sp)
    MIXSPLIT(mw, w_sp)
    MIXSPLIT(mk, k_sp)
    MIXSPLIT(mv, v_sp)
    MIXSPLIT(ma, a_sp)
    MIXSPLIT(mg, g_sp)
#undef MIXSPLIT
}

// ---------------------------------------------------------------------------
// transpose + split-convert weight [960][960] -> [N][K] hi/lo (single)
// ---------------------------------------------------------------------------
__global__ __launch_bounds__(256) void convWT_kernel(
    const float* __restrict__ W, ushort* __restrict__ Thi, ushort* __restrict__ Tlo)
{
    __shared__ float tile[32][33];
    int k0 = blockIdx.x * 32, n0 = blockIdx.y * 32;
    int tx = threadIdx.x & 31, ty = threadIdx.x >> 5;  // 32 x 8
#pragma unroll
    for (int i = 0; i < 4; ++i)
        tile[ty + 8 * i][tx] = W[(size_t)(k0 + ty + 8 * i) * 960 + n0 + tx];
    __syncthreads();
#pragma unroll
    for (int i = 0; i < 4; ++i) {
        float x = tile[tx][ty + 8 * i];
        ushort h = f2bf(x);
        ushort l = f2bf(x - bf2f(h));
        size_t o = (size_t)(n0 + ty + 8 * i) * 960 + k0 + tx;
        Thi[o] = h;
        Tlo[o] = l;
    }
}

// merged z=3: Wr->S0, Wk->S1, Wv->S2
__global__ __launch_bounds__(256) void convWT3_kernel(
    const float* __restrict__ Wr, const float* __restrict__ Wk,
    const float* __restrict__ Wv,
    ushort* __restrict__ S0, ushort* __restrict__ S1, ushort* __restrict__ S2)
{
    __shared__ float tile[32][33];
    int z = blockIdx.z;
    const float* W = (z == 0) ? Wr : (z == 1) ? Wk : Wv;
    ushort* Thi = (z == 0) ? S0 : (z == 1) ? S1 : S2;
    ushort* Tlo = Thi + (size_t)960 * 960;
    int k0 = blockIdx.x * 32, n0 = blockIdx.y * 32;
    int tx = threadIdx.x & 31, ty = threadIdx.x >> 5;
#pragma unroll
    for (int i = 0; i < 4; ++i)
        tile[ty + 8 * i][tx] = W[(size_t)(k0 + ty + 8 * i) * 960 + n0 + tx];
    __syncthreads();
#pragma unroll
    for (int i = 0; i < 4; ++i) {
        float x = tile[tx][ty + 8 * i];
        ushort h = f2bf(x);
        ushort l = f2bf(x - bf2f(h));
        size_t o = (size_t)(n0 + ty + 8 * i) * 960 + k0 + tx;
        Thi[o] = h;
        Tlo[o] = l;
    }
}

// ---------------------------------------------------------------------------
// LoRA weight prep
// ---------------------------------------------------------------------------
__global__ __launch_bounds__(256) void wprep_kernel(
    const float* __restrict__ w1, const float* __restrict__ a1,
    const float* __restrict__ v1, const float* __restrict__ g1,
    const float* __restrict__ w2, const float* __restrict__ a2,
    const float* __restrict__ v2, const float* __restrict__ g2,
    ushort* __restrict__ arena)
{
    __shared__ float tile[32][33];
    int z = blockIdx.z;
    const float* src;
    int K, N;
    size_t off;
    switch (z) {
        case 0: src = w1; K = 960; N = 64;  off = 0;      break;
        case 1: src = a1; K = 960; N = 64;  off = 122880; break;
        case 2: src = v1; K = 960; N = 32;  off = 245760; break;
        case 3: src = g1; K = 960; N = 128; off = 307200; break;
        case 4: src = w2; K = 64;  N = 960; off = 552960; break;
        case 5: src = a2; K = 64;  N = 960; off = 675840; break;
        case 6: src = v2; K = 32;  N = 960; off = 798720; break;
        default: src = g2; K = 128; N = 960; off = 860160; break;
    }
    int k0 = blockIdx.x * 32, n0 = blockIdx.y * 32;
    if (k0 >= K || n0 >= N) return;
    int tx = threadIdx.x & 31, ty = threadIdx.x >> 5;
#pragma unroll
    for (int i = 0; i < 4; ++i)
        tile[ty + 8 * i][tx] = src[(size_t)(k0 + ty + 8 * i) * N + n0 + tx];
    __syncthreads();
    ushort* Thi = arena + off;
    ushort* Tlo = arena + off + (size_t)K * N;
#pragma unroll
    for (int i = 0; i < 4; ++i) {
        float x = tile[tx][ty + 8 * i];
        ushort h = f2bf(x);
        ushort l = f2bf(x - bf2f(h));
        size_t o = (size_t)(n0 + ty + 8 * i) * K + k0 + tx;
        Thi[o] = h;
        Tlo[o] = l;
    }
}

// ---------------------------------------------------------------------------
// split-bf16 MFMA GEMM core, 256 threads / 4 waves, BM=128 BN=64 BK=32.
// R23 PROVEN version: global_load_lds staging, XOR-swizzled layout, 2-buffer
// 48KB static LDS, vmcnt(0)+barrier per k-step. (3-buffer counted-vmcnt ring
// closed permanently: NaN with both static 72KB — over the 64KB launch cap —
// and dynamic LDS in R21/R22/R24.)
// ---------------------------------------------------------------------------
__device__ __forceinline__ void gemm_core(
    const ushort* __restrict__ Ahi, const ushort* __restrict__ Alo,
    const ushort* __restrict__ Bhi, const ushort* __restrict__ Blo,
    float* __restrict__ C, int ldc, int bm, int bn)
{
    __shared__ __align__(16) ushort sA[2][2][128][32];  // 32768 B
    __shared__ __align__(16) ushort sB[2][2][64][32];   // 16384 B
    const int K = 960;
    int t = threadIdx.x;
    int w = t >> 6, l = t & 63;
    int lr = l & 15, lk = l >> 4;
    int lks = lk ^ ((lr >> 1) & 3);   // swizzled read chunk

    int srow = l >> 2;
    int skc = ((l & 3) ^ ((l >> 3) & 3)) * 8;
    const ushort* gA0h = Ahi + (size_t)(bm + 32 * w + srow) * K + skc;
    const ushort* gA1h = Ahi + (size_t)(bm + 32 * w + 16 + srow) * K + skc;
    const ushort* gA0l = Alo + (size_t)(bm + 32 * w + srow) * K + skc;
    const ushort* gA1l = Alo + (size_t)(bm + 32 * w + 16 + srow) * K + skc;
    const ushort* gBh = Bhi + (size_t)(bn + 16 * w + srow) * K + skc;
    const ushort* gBl = Blo + (size_t)(bn + 16 * w + srow) * K + skc;

    f32x4 acc[2][4];
#pragma unroll
    for (int i = 0; i < 2; ++i)
#pragma unroll
        for (int j = 0; j < 4; ++j)
#pragma unroll
            for (int e = 0; e < 4; ++e) acc[i][j][e] = 0.f;

#define STAGE(BUF, KOFF)                                                      \
    {                                                                         \
        GLOAD16(gA0h + (KOFF), &sA[BUF][0][32 * w][0]);                       \
        GLOAD16(gA1h + (KOFF), &sA[BUF][0][32 * w + 16][0]);                  \
        GLOAD16(gA0l + (KOFF), &sA[BUF][1][32 * w][0]);                       \
        GLOAD16(gA1l + (KOFF), &sA[BUF][1][32 * w + 16][0]);                  \
        GLOAD16(gBh + (KOFF), &sB[BUF][0][16 * w][0]);                        \
        GLOAD16(gBl + (KOFF), &sB[BUF][1][16 * w][0]);                        \
    }
#define COMPUTEK(BUF)                                                         \
    {                                                                         \
        bf16x8 ah[2], al[2], bh[4], bl[4];                                    \
        _Pragma("unroll")                                                     \
        for (int i = 0; i < 2; ++i) {                                         \
            ah[i] = *(const bf16x8*)&sA[BUF][0][32 * w + 16 * i + lr][lks * 8];\
            al[i] = *(const bf16x8*)&sA[BUF][1][32 * w + 16 * i + lr][lks * 8];\
        }                                                                     \
        _Pragma("unroll")                                                     \
        for (int j = 0; j < 4; ++j) {                                         \
            bh[j] = *(const bf16x8*)&sB[BUF][0][16 * j + lr][lks * 8];        \
            bl[j] = *(const bf16x8*)&sB[BUF][1][16 * j + lr][lks * 8];        \
        }                                                                     \
        _Pragma("unroll")                                                     \
        for (int i = 0; i < 2; ++i)                                           \
            _Pragma("unroll")                                                 \
            for (int j = 0; j < 4; ++j) {                                     \
                acc[i][j] = __builtin_amdgcn_mfma_f32_16x16x32_bf16(          \
                    ah[i], bh[j], acc[i][j], 0, 0, 0);                        \
                acc[i][j] = __builtin_amdgcn_mfma_f32_16x16x32_bf16(          \
                    ah[i], bl[j], acc[i][j], 0, 0, 0);                        \
                acc[i][j] = __builtin_amdgcn_mfma_f32_16x16x32_bf16(          \
                    al[i], bh[j], acc[i][j], 0, 0, 0);                        \
            }                                                                 \
    }

    STAGE(0, 0)
    asm volatile("s_waitcnt vmcnt(0)" ::: "memory");
    __builtin_amdgcn_s_barrier();

    int cur = 0;
    for (int ks = 0; ks < 30; ++ks) {
        if (ks + 1 < 30) STAGE(cur ^ 1, (ks + 1) * 32)
        COMPUTEK(cur)
        asm volatile("s_waitcnt vmcnt(0) lgkmcnt(0)" ::: "memory");
        __builtin_amdgcn_s_barrier();
        cur ^= 1;
    }

#pragma unroll
    for (int i = 0; i < 2; ++i)
#pragma unroll
        for (int j = 0; j < 4; ++j)
#pragma unroll
            for (int jr = 0; jr < 4; ++jr) {
                int row = bm + 32 * w + 16 * i + lk * 4 + jr;
                int col = bn + 16 * j + lr;
                C[(size_t)row * ldc + col] = acc[i][j][jr];
            }
#undef COMPUTEK
#undef STAGE
}

// merged stage-1: z=0 r, z=1 k, z=2 v
__global__ __launch_bounds__(256) void gemm3_kernel(
    const ushort* __restrict__ XR, const ushort* __restrict__ XK,
    const ushort* __restrict__ XV,
    const ushort* __restrict__ WrS, const ushort* __restrict__ WkS,
    const ushort* __restrict__ WvS,
    float* __restrict__ oR, float* __restrict__ oK, float* __restrict__ oV)
{
    int z = blockIdx.z;
    const ushort* A = (z == 0) ? XR : (z == 1) ? XK : XV;
    const ushort* W = (z == 0) ? WrS : (z == 1) ? WkS : WvS;
    float* C = (z == 0) ? oR : (z == 1) ? oK : oV;
    gemm_core(A, A + MCc, W, W + (size_t)960 * 960, C, Cn,
              blockIdx.x * 128, blockIdx.y * 64);
}

__global__ __launch_bounds__(256) void gemm1_kernel(
    const ushort* __restrict__ Ahi, const ushort* __restrict__ Alo,
    const ushort* __restrict__ Bhi, const ushort* __restrict__ Blo,
    float* __restrict__ C, int ldc)
{
    gemm_core(Ahi, Alo, Bhi, Blo, C, ldc, blockIdx.x * 128, blockIdx.y * 64);
}

// ---------------------------------------------------------------------------
// generic split-bf16 MFMA core for LoRA (512 threads).
// NEW: optional split-pair output (Chi/Clo non-null) — activation applied,
// then f2bf hi/lo written directly (replaces the separate convN pass).
// ---------------------------------------------------------------------------
__device__ __forceinline__ void lora_core(
    const ushort* __restrict__ Ahi, const ushort* __restrict__ Alo, int lda,
    const ushort* __restrict__ Bhi, const ushort* __restrict__ Blo,
    float* __restrict__ C, ushort* __restrict__ Chi, ushort* __restrict__ Clo,
    int ldc, int Nvalid, int K, int act, int bn)
{
    __shared__ __align__(16) ushort sA[2][2][128][40];
    __shared__ __align__(16) ushort sB[2][2][64][40];
    int bm = blockIdx.x * 128;
    int t = threadIdx.x;
    int w = t >> 6, l = t & 63;
    int lr = l & 15, lk = l >> 4;

    int ar = t >> 2, aseg = t & 3;
    int brr = t >> 2;
    int bhl = brr >> 6, brow = brr & 63, bseg = t & 3;
    const ushort* gAh = Ahi + (size_t)(bm + ar) * lda + aseg * 8;
    const ushort* gAl = Alo + (size_t)(bm + ar) * lda + aseg * 8;
    const ushort* gB = (bhl ? Blo : Bhi) + (size_t)(bn + brow) * K + bseg * 8;

    f32x4 acc[4];
#pragma unroll
    for (int j = 0; j < 4; ++j)
#pragma unroll
        for (int e = 0; e < 4; ++e) acc[j][e] = 0.f;

    float4 rhP, rlP, rbP, rhQ, rlQ, rbQ;
#define LLOADP(KOFF)                                                          \
    {                                                                         \
        rhP = *(const float4*)(gAh + (KOFF));                                 \
        rlP = *(const float4*)(gAl + (KOFF));                                 \
        rbP = *(const float4*)(gB + (KOFF));                                  \
    }
#define LLOADQ(KOFF)                                                          \
    {                                                                         \
        rhQ = *(const float4*)(gAh + (KOFF));                                 \
        rlQ = *(const float4*)(gAl + (KOFF));                                 \
        rbQ = *(const float4*)(gB + (KOFF));                                  \
    }
#define LWRITEP(BUF)                                                          \
    {                                                                         \
        *(float4*)&sA[BUF][0][ar][aseg * 8] = rhP;                            \
        *(float4*)&sA[BUF][1][ar][aseg * 8] = rlP;                            \
        *(float4*)&sB[BUF][bhl][brow][bseg * 8] = rbP;                        \
    }
#define LWRITEQ(BUF)                                                          \
    {                                                                         \
        *(float4*)&sA[BUF][0][ar][aseg * 8] = rhQ;                            \
        *(float4*)&sA[BUF][1][ar][aseg * 8] = rlQ;                            \
        *(float4*)&sB[BUF][bhl][brow][bseg * 8] = rbQ;                        \
    }
#define LCOMPUTE(BUF)                                                         \
    {                                                                         \
        bf16x8 ah, al, bh[4], bl[4];                                          \
        ah = *(const bf16x8*)&sA[BUF][0][16 * w + lr][lk * 8];                \
        al = *(const bf16x8*)&sA[BUF][1][16 * w + lr][lk * 8];                \
        _Pragma("unroll")                                                     \
        for (int j = 0; j < 4; ++j) {                                         \
            bh[j] = *(const bf16x8*)&sB[BUF][0][16 * j + lr][lk * 8];         \
            bl[j] = *(const bf16x8*)&sB[BUF][1][16 * j + lr][lk * 8];         \
        }                                                                     \
        _Pragma("unroll")                                                     \
        for (int j = 0; j < 4; ++j) {                                         \
            acc[j] = __builtin_amdgcn_mfma_f32_16x16x32_bf16(ah, bh[j], acc[j], 0, 0, 0); \
            acc[j] = __builtin_amdgcn_mfma_f32_16x16x32_bf16(ah, bl[j], acc[j], 0, 0, 0); \
            acc[j] = __builtin_amdgcn_mfma_f32_16x16x32_bf16(al, bh[j], acc[j], 0, 0, 0); \
        }                                                                     \
    }

    int nk = K >> 5;
    LLOADP(0)
    LWRITEP(0)
    if (nk > 1) LLOADQ(32)
    asm volatile("s_waitcnt lgkmcnt(0)" ::: "memory");
    __builtin_amdgcn_s_barrier();

    int cur = 0;
    for (int ks = 0; ks < nk; ++ks) {
        int k2 = (ks + 2 < nk ? ks + 2 : nk - 1) * 32;
        if (!(ks & 1)) { LLOADP(k2) } else { LLOADQ(k2) }
        LCOMPUTE(cur)
        if (ks + 1 < nk) {
            if (!(ks & 1)) { LWRITEQ(cur ^ 1) } else { LWRITEP(cur ^ 1) }
            asm volatile("s_waitcnt lgkmcnt(0)" ::: "memory");
            __builtin_amdgcn_s_barrier();
        }
        cur ^= 1;
    }

#pragma unroll
    for (int j = 0; j < 4; ++j)
#pragma unroll
        for (int jr = 0; jr < 4; ++jr) {
            int row = bm + 16 * w + lk * 4 + jr;
            int col = bn + 16 * j + lr;
            if (col < Nvalid) {
                float v = acc[j][jr];
                if (act == 1) v = tanhf(v);
                else if (act == 2) v = sigmf(v);
                if (Chi) {
                    ushort h = f2bf(v);
                    ushort lo = f2bf(v - bf2f(h));
                    Chi[(size_t)row * ldc + col] = h;
                    Clo[(size_t)row * ldc + col] = lo;
                } else {
                    C[(size_t)row * ldc + col] = v;
                }
            }
        }
#undef LCOMPUTE
#undef LWRITEP
#undef LWRITEQ
#undef LLOADP
#undef LLOADQ
}

// LoRA-down MFMA: grid (32, 2, 4) — writes hid split pair directly
__global__ __launch_bounds__(512) void lora_down_kernel(
    const ushort* __restrict__ xw_sp, const ushort* __restrict__ xa_sp,
    const ushort* __restrict__ xv_sp, const ushort* __restrict__ xg_sp,
    const ushort* __restrict__ arena,
    ushort* __restrict__ hidHi, ushort* __restrict__ hidLo)
{
    int z = blockIdx.z;
    int bn = blockIdx.y * 64;
    const ushort* A;
    size_t off;
    int N, act, coff;
    switch (z) {
        case 0: A = xw_sp; off = 0;      N = 64;  act = 1; coff = 0;   break;
        case 1: A = xa_sp; off = 122880; N = 64;  act = 0; coff = 64;  break;
        case 2: A = xv_sp; off = 245760; N = 32;  act = 0; coff = 128; break;
        default: A = xg_sp; off = 307200; N = 128; act = 2; coff = 160; break;
    }
    if (bn >= N) return;
    lora_core(A, A + MCc, Cn, arena + off, arena + off + (size_t)960 * N,
              nullptr, hidHi + coff, hidLo + coff, 288, N, 960, act, bn);
}

// LoRA-up MFMA: grid (32, 15, 4)
__global__ __launch_bounds__(512) void lora_up_kernel(
    const ushort* __restrict__ hidHi, const ushort* __restrict__ hidLo,
    const ushort* __restrict__ arena,
    float* __restrict__ oW, float* __restrict__ oA,
    float* __restrict__ oV, float* __restrict__ oG)
{
    int z = blockIdx.z;
    int bn = blockIdx.y * 64;
    size_t off;
    int K, aoff;
    float* C;
    switch (z) {
        case 0: off = 552960; K = 64;  aoff = 0;   C = oW; break;
        case 1: off = 675840; K = 64;  aoff = 64;  C = oA; break;
        case 2: off = 798720; K = 32;  aoff = 128; C = oV; break;
        default: off = 860160; K = 128; aoff = 160; C = oG; break;
    }
    lora_core(hidHi + aoff, hidLo + aoff, 288, arena + off,
              arena + off + (size_t)K * 960, C, nullptr, nullptr,
              Cn, Cn, K, 0, bn);
}

// ---------------------------------------------------------------------------
// SEQUENCE-PARALLEL chunked scan: 8 segments (480 blocks), 16-step chunks,
// 32-step warmup (R23 proven config).
// ---------------------------------------------------------------------------
__global__ __launch_bounds__(256, 2) void scan_kernel(
    const float* __restrict__ rP, const float* __restrict__ wrawP,
    const float* __restrict__ apreP, const float* __restrict__ vsigP,
    const float* __restrict__ krawP, const float* __restrict__ vrawP,
    const float* __restrict__ vfirstP, const float* __restrict__ gP,
    const float* __restrict__ w0, const float* __restrict__ a0,
    const float* __restrict__ v0c, const float* __restrict__ kkc,
    const float* __restrict__ kac, const float* __restrict__ r_k,
    const float* __restrict__ ln_g, const float* __restrict__ ln_b,
    ushort* __restrict__ xsp)
{
    __shared__ float buf[2][7][16][64];  // 57344 B
    __shared__ float outL[16][64];       // 4096 B
    int tid = threadIdx.x;
    int q = tid >> 6, l = tid & 63;
    int blk = blockIdx.x;
    int bh = blk >> 3, seg = blk & 7;
    int bb = bh / Hn, h = bh - bb * Hn;
    size_t base = (size_t)bb * Tn * Cn + h * 64;
    int rg = l >> 4, cg = l & 15;
    int row0 = 16 * q + 4 * rg;
    int c0 = 4 * cg;

    int sstep = tid >> 4, sseg = tid & 15;
    size_t soff = base + (size_t)sstep * Cn + sseg * 4;
    int wofs = sstep * 64 + sseg * 4;
    int ccol = h * 64 + sseg * 4;

    int cbeg = (seg == 0) ? 0 : 8 * seg - 2;
    int cendc = 8 * seg + 8;
    int coutc = 8 * seg;

    float4 w0c4 = *(const float4*)(w0 + ccol);
    float4 a0c4 = *(const float4*)(a0 + ccol);
    float4 v0c4 = *(const float4*)(v0c + ccol);
    float4 kkc4 = *(const float4*)(kkc + ccol);
    float4 kac4 = *(const float4*)(kac + ccol);
    float4 rk4 = *(const float4*)(r_k + ccol);
    float4 lg4 = *(const float4*)(ln_g + ccol);
    float4 lb4 = *(const float4*)(ln_b + ccol);

    float s[4][4];
#pragma unroll
    for (int r = 0; r < 4; ++r)
#pragma unroll
        for (int c = 0; c < 4; ++c) s[r][c] = 0.f;

    float4 g_r, g_wr, g_vr, g_vf, g_vs, g_g, g_kr, g_ap;

#define LOADSTAGE(OFF)                                                        \
    g_r = *(const float4*)(rP + soff + (OFF));                                \
    g_wr = *(const float4*)(wrawP + soff + (OFF));                            \
    g_vr = *(const float4*)(vrawP + soff + (OFF));                            \
    g_vf = *(const float4*)(vfirstP + soff + (OFF));                          \
    g_vs = *(const float4*)(vsigP + soff + (OFF));                            \
    g_g = *(const float4*)(gP + soff + (OFF));                                \
    g_kr = *(const float4*)(krawP + soff + (OFF));                            \
    g_ap = *(const float4*)(apreP + soff + (OFF));

#define PARK(BN)                                                              \
    {                                                                         \
        const float E = 0.60653065971263342f;                                 \
        float4 w4;                                                            \
        w4.x = sigmf(w0c4.x + g_wr.x) * E;                                    \
        w4.y = sigmf(w0c4.y + g_wr.y) * E;                                    \
        w4.z = sigmf(w0c4.z + g_wr.z) * E;                                    \
        w4.w = sigmf(w0c4.w + g_wr.w) * E;                                    \
        float4 v4;                                                            \
        v4.x = g_vr.x + (g_vf.x - g_vr.x) * sigmf(v0c4.x + g_vs.x);           \
        v4.y = g_vr.y + (g_vf.y - g_vr.y) * sigmf(v0c4.y + g_vs.y);           \
        v4.z = g_vr.z + (g_vf.z - g_vr.z) * sigmf(v0c4.z + g_vs.z);           \
        v4.w = g_vr.w + (g_vf.w - g_vr.w) * sigmf(v0c4.w + g_vs.w);           \
        float4 a4;                                                            \
        a4.x = sigmf(a0c4.x + g_ap.x);                                        \
        a4.y = sigmf(a0c4.y + g_ap.y);                                        \
        a4.z = sigmf(a0c4.z + g_ap.z);                                        \
        a4.w = sigmf(a0c4.w + g_ap.w);                                        \
        float4 kk;                                                            \
        kk.x = g_kr.x * kkc4.x; kk.y = g_kr.y * kkc4.y;                       \
        kk.z = g_kr.z * kkc4.z; kk.w = g_kr.w * kkc4.w;                       \
        float ss = kk.x * kk.x + kk.y * kk.y + kk.z * kk.z + kk.w * kk.w;     \
        ss = rowsum16(ss);                                                    \
        float inv = 1.0f / fmaxf(sqrtf(ss), 1e-12f);                          \
        float4 ah4, bh4, kh4;                                                 \
        ah4.x = -kk.x * inv; bh4.x = kk.x * inv * a4.x;                       \
        ah4.y = -kk.y * inv; bh4.y = kk.y * inv * a4.y;                       \
        ah4.z = -kk.z * inv; bh4.z = kk.z * inv * a4.z;                       \
        ah4.w = -kk.w * inv; bh4.w = kk.w * inv * a4.w;                       \
        kh4.x = g_kr.x * (1.0f + (a4.x - 1.0f) * kac4.x);                     \
        kh4.y = g_kr.y * (1.0f + (a4.y - 1.0f) * kac4.y);                     \
        kh4.z = g_kr.z * (1.0f + (a4.z - 1.0f) * kac4.z);                     \
        kh4.w = g_kr.w * (1.0f + (a4.w - 1.0f) * kac4.w);                     \
        *(float4*)((BN) + 0 * 1024 + wofs) = g_r;                             \
        *(float4*)((BN) + 1 * 1024 + wofs) = w4;                              \
        *(float4*)((BN) + 2 * 1024 + wofs) = kh4;                             \
        *(float4*)((BN) + 3 * 1024 + wofs) = ah4;                             \
        *(float4*)((BN) + 4 * 1024 + wofs) = bh4;                             \
        *(float4*)((BN) + 5 * 1024 + wofs) = v4;                              \
        *(float4*)((BN) + 6 * 1024 + wofs) = g_g;                             \
    }

    LOADSTAGE((size_t)cbeg * 16 * Cn)
    PARK(&buf[0][0][0][0])
    asm volatile("s_waitcnt lgkmcnt(0)" ::: "memory");
    __builtin_amdgcn_s_barrier();

#define DECL2(S)                                                              \
    float4 S##a0, S##w0, S##k0, S##b0, S##r0, S##v0;                          \
    float4 S##a1, S##w1, S##k1, S##b1, S##r1, S##v1;
#define DSLOAD2(S, T)                                                         \
    S##a0 = *(const float4*)(bc + 3 * 1024 + (T) * 64 + c0);                  \
    S##w0 = *(const float4*)(bc + 1 * 1024 + (T) * 64 + c0);                  \
    S##k0 = *(const float4*)(bc + 2 * 1024 + (T) * 64 + c0);                  \
    S##b0 = *(const float4*)(bc + 4 * 1024 + (T) * 64 + c0);                  \
    S##r0 = *(const float4*)(bc + 0 * 1024 + (T) * 64 + c0);                  \
    S##v0 = *(const float4*)(bc + 5 * 1024 + (T) * 64 + row0);                \
    S##a1 = *(const float4*)(bc + 3 * 1024 + ((T) + 1) * 64 + c0);            \
    S##w1 = *(const float4*)(bc + 1 * 1024 + ((T) + 1) * 64 + c0);            \
    S##k1 = *(const float4*)(bc + 2 * 1024 + ((T) + 1) * 64 + c0);            \
    S##b1 = *(const float4*)(bc + 4 * 1024 + ((T) + 1) * 64 + c0);            \
    S##r1 = *(const float4*)(bc + 0 * 1024 + ((T) + 1) * 64 + c0);            \
    S##v1 = *(const float4*)(bc + 5 * 1024 + ((T) + 1) * 64 + row0);
#define STEP(AV, WV, KV, BV, RV, VV, T)                                       \
    {                                                                         \
        float sp0 = s[0][0] * AV.x + s[0][1] * AV.y + s[0][2] * AV.z + s[0][3] * AV.w; \
        float sp1 = s[1][0] * AV.x + s[1][1] * AV.y + s[1][2] * AV.z + s[1][3] * AV.w; \
        float sp2 = s[2][0] * AV.x + s[2][1] * AV.y + s[2][2] * AV.z + s[2][3] * AV.w; \
        float sp3 = s[3][0] * AV.x + s[3][1] * AV.y + s[3][2] * AV.z + s[3][3] * AV.w; \
        sp0 = rowsum16(sp0);                                                  \
        sp1 = rowsum16(sp1);                                                  \
        sp2 = rowsum16(sp2);                                                  \
        sp3 = rowsum16(sp3);                                                  \
        float sa[4] = {sp0, sp1, sp2, sp3};                                   \
        float vr[4] = {VV.x, VV.y, VV.z, VV.w};                               \
        float op[4];                                                          \
        _Pragma("unroll")                                                     \
        for (int r = 0; r < 4; ++r) {                                         \
            s[r][0] = s[r][0] * WV.x + sa[r] * BV.x + vr[r] * KV.x;           \
            float o = s[r][0] * RV.x;                                         \
            s[r][1] = s[r][1] * WV.y + sa[r] * BV.y + vr[r] * KV.y;           \
            o += s[r][1] * RV.y;                                              \
            s[r][2] = s[r][2] * WV.z + sa[r] * BV.z + vr[r] * KV.z;           \
            o += s[r][2] * RV.z;                                              \
            s[r][3] = s[r][3] * WV.w + sa[r] * BV.w + vr[r] * KV.w;           \
            o += s[r][3] * RV.w;                                              \
            op[r] = rowsum16(o);                                              \
        }                                                                     \
        if (cg == 0)                                                          \
            *(float4*)&outL[T][row0] = make_float4(op[0], op[1], op[2], op[3]); \
    }

    DECL2(A) DECL2(B)

    int cur = 0;
    for (int c = cbeg; c < cendc; ++c) {
        const float* bc = &buf[cur][0][0][0];
        {
            int cnxt = (c + 1 < cendc) ? c + 1 : c;
            LOADSTAGE((size_t)cnxt * 16 * Cn)
        }

        DSLOAD2(A, 0)
#pragma unroll
        for (int it = 0; it < 4; ++it) {
            DSLOAD2(B, 4 * it + 2)
            STEP(Aa0, Aw0, Ak0, Ab0, Ar0, Av0, 4 * it + 0)
            STEP(Aa1, Aw1, Ak1, Ab1, Ar1, Av1, 4 * it + 1)
            if (it < 3) { DSLOAD2(A, 4 * it + 4) }
            STEP(Ba0, Bw0, Bk0, Bb0, Br0, Bv0, 4 * it + 2)
            STEP(Ba1, Bw1, Bk1, Bb1, Br1, Bv1, 4 * it + 3)
        }

        PARK(&buf[cur ^ 1][0][0][0])
        asm volatile("s_waitcnt lgkmcnt(0)" ::: "memory");
        __builtin_amdgcn_s_barrier();

        if (c >= coutc) {
            float4 o4 = *(const float4*)&outL[sstep][4 * sseg];
            float4 r4 = *(const float4*)(bc + 0 * 1024 + sstep * 64 + 4 * sseg);
            float4 k4 = *(const float4*)(bc + 2 * 1024 + sstep * 64 + 4 * sseg);
            float4 v4 = *(const float4*)(bc + 5 * 1024 + sstep * 64 + 4 * sseg);
            float4 gg4 = *(const float4*)(bc + 6 * 1024 + sstep * 64 + 4 * sseg);
            float m1 = o4.x + o4.y + o4.z + o4.w;
            float m2 = o4.x * o4.x + o4.y * o4.y + o4.z * o4.z + o4.w * o4.w;
            float bd = r4.x * k4.x * rk4.x + r4.y * k4.y * rk4.y +
                       r4.z * k4.z * rk4.z + r4.w * k4.w * rk4.w;
            m1 = rowsum16(m1);
            m2 = rowsum16(m2);
            bd = rowsum16(bd);
            float mean = m1 * (1.f / 64.f);
            float var = m2 * (1.f / 64.f) - mean * mean;
            float is = rsqrtf(var + 0.00064f);
            float xo0 = ((o4.x - mean) * is * lg4.x + lb4.x + bd * v4.x) * gg4.x;
            float xo1 = ((o4.y - mean) * is * lg4.y + lb4.y + bd * v4.y) * gg4.y;
            float xo2 = ((o4.z - mean) * is * lg4.z + lb4.z + bd * v4.z) * gg4.z;
            float xo3 = ((o4.w - mean) * is * lg4.w + lb4.w + bd * v4.w) * gg4.w;
            ushort h0 = f2bf(xo0), h1 = f2bf(xo1), h2 = f2bf(xo2), h3 = f2bf(xo3);
            ushort l0 = f2bf(xo0 - bf2f(h0)), l1 = f2bf(xo1 - bf2f(h1));
            ushort l2 = f2bf(xo2 - bf2f(h2)), l3 = f2bf(xo3 - bf2f(h3));
            size_t gt = (size_t)c * 16 + sstep;
            size_t eo = base + gt * Cn + 4 * sseg;
            *(ushort4*)(xsp + eo) = make_ushort4(h0, h1, h2, h3);
            *(ushort4*)(xsp + MCc + eo) = make_ushort4(l0, l1, l2, l3);
        }
        __builtin_amdgcn_s_barrier();
        cur ^= 1;
    }
#undef STEP
#undef DSLOAD2
#undef DECL2
#undef PARK
#undef LOADSTAGE
}

// ---------------------------------------------------------------------------
extern "C" void kernel_launch(void* const* d_in, const int* in_sizes, int n_in,
                              void* d_out, int out_size, void* d_ws, size_t ws_size,
                              hipStream_t stream)
{
    const float* x       = (const float*)d_in[0];
    const float* v_first = (const float*)d_in[1];
    const float* x_r     = (const float*)d_in[2];
    const float* x_w     = (const float*)d_in[3];
    const float* x_k     = (const float*)d_in[4];
    const float* x_v     = (const float*)d_in[5];
    const float* x_a     = (const float*)d_in[6];
    const float* x_g     = (const float*)d_in[7];
    const float* w0      = (const float*)d_in[8];
    const float* w1      = (const float*)d_in[9];
    const float* w2      = (const float*)d_in[10];
    const float* a0      = (const float*)d_in[11];
    const float* a1      = (const float*)d_in[12];
    const float* a2      = (const float*)d_in[13];
    const float* v0c     = (const float*)d_in[14];
    const float* v1      = (const float*)d_in[15];
    const float* v2      = (const float*)d_in[16];
    const float* g1w     = (const float*)d_in[17];
    const float* g2w     = (const float*)d_in[18];
    const float* k_k     = (const float*)d_in[19];
    const float* k_a     = (const float*)d_in[20];
    const float* r_k     = (const float*)d_in[21];
    const float* Wr      = (const float*)d_in[22];
    const float* Wk      = (const float*)d_in[23];
    const float* Wv      = (const float*)d_in[24];
    const float* Wo      = (const float*)d_in[25];
    const float* ln_g    = (const float*)d_in[26];
    const float* ln_b    = (const float*)d_in[27];
    float* out = (float*)d_out;

    float* ws = (float*)d_ws;
    float* B0 = ws + 0 * MCc;  // xr split pair -> wraw f32
    float* B1 = ws + 1 * MCc;  // xw split pair -> vsigp f32
    float* B2 = ws + 2 * MCc;  // xk split pair -> apre f32
    float* B3 = ws + 3 * MCc;  // scratch: hid split + arena + Wk/Wv splits
    float* B4 = ws + 4 * MCc;  // xa split pair -> xog split pair (scan out)
    float* B5 = ws + 5 * MCc;  // xg split pair -> g f32
    float* B6 = ws + 6 * MCc;  // r f32
    float* B7 = ws + 7 * MCc;  // k raw f32
    float* B8 = ws + 8 * MCc;  // v raw f32
    float* hid = ws + 9 * MCc; // scratch: Wr/Wo split

    ushort* XRsp = (ushort*)B0;
    ushort* XWsp = (ushort*)B1;
    ushort* XKsp = (ushort*)B2;
    ushort* XVsp = (ushort*)out;  // d_out scratch until stage 5
    ushort* XAsp = (ushort*)B4;
    ushort* XGsp = (ushort*)B5;
    ushort* S3 = (ushort*)B3;
    ushort* hidHi = S3;                     // 1,179,648
    ushort* hidLo = S3 + 1179648;           // 1,179,648
    ushort* arena = S3 + 2359296;           // 1,105,920
    ushort* WkS = S3 + 3465216;             // 1,843,200
    ushort* WvS = S3 + 5308416;             // 1,843,200 (ends 7,151,616 < 7,864,320)
    ushort* WrS = (ushort*)hid;             // 1,843,200 < 2,359,296 cap
    ushort* Whi = (ushort*)hid;             // Wo split later
    ushort* Wlo = Whi + (size_t)960 * 960;
    ushort* Xsp = (ushort*)B4;              // scan output split pair

    mix6_kernel<<<3840, 256, 0, stream>>>(x, x_r, x_w, x_k, x_v, x_a, x_g,
                                          XRsp, XWsp, XKsp, XVsp, XAsp, XGsp);
    wprep_kernel<<<dim3(30, 30, 8), 256, 0, stream>>>(w1, a1, v1, g1w,
                                                      w2, a2, v2, g2w, arena);
    // stage 1: all three weight splits in one dispatch, then merged GEMM
    convWT3_kernel<<<dim3(30, 30, 3), 256, 0, stream>>>(Wr, Wk, Wv,
                                                        WrS, WkS, WvS);
    gemm3_kernel<<<dim3(32, 15, 3), 256, 0, stream>>>(XRsp, XKsp, XVsp,
                                                      WrS, WkS, WvS,
                                                      B6, B7, B8);
    // stage 2: LoRA-down via MFMA (fused tanh/sigmoid + split-pair output)
    lora_down_kernel<<<dim3(32, 2, 4), 512, 0, stream>>>(XWsp, XAsp, XVsp, XGsp,
                                                         arena, hidHi, hidLo);
    // stage 3: LoRA-up via MFMA -> B0=wraw, B2=apre, B1=vsigp, B5=g
    lora_up_kernel<<<dim3(32, 15, 4), 512, 0, stream>>>(hidHi, hidLo, arena,
                                                        B0, B2, B1, B5);
    // Wo split (hid scratch free after gemm3 consumed WrS)
    convWT_kernel<<<dim3(30, 30), 256, 0, stream>>>(Wo, Whi, Wlo);
    // stage 4: sequence-parallel scan, 8 segments (32-step warmup),
    // fused stage3e + norm/bonus/gate -> split pair in B4
    scan_kernel<<<480, 256, 0, stream>>>(B6, B0, B2, B1, B7, B8, v_first, B5,
                                         w0, a0, v0c, k_k, k_a,
                                         r_k, ln_g, ln_b, Xsp);
    // stage 5: output projection
    gemm1_kernel<<<dim3(32, 15), 256, 0, stream>>>(Xsp, Xsp + MCc, Whi, Wlo,
                                                   out, Cn);
}

// Round 26
// 293.975 us; speedup vs baseline: 1.0702x; 1.0371x over previous
//
#include <hip/hip_runtime.h>
#include <hip/hip_bf16.h>
#include <math.h>

#define Tn 1024
#define Cn 960
#define Hn 15
#define Nn 64
#define Mn 4096  // B*T

typedef short bf16x8 __attribute__((ext_vector_type(8)));
typedef float f32x4 __attribute__((ext_vector_type(4)));

#define MCc ((size_t)Mn * Cn)

__device__ __forceinline__ float sigmf(float x) { return 1.0f / (1.0f + __expf(-x)); }

// round-to-nearest-even f32 -> bf16 (as ushort)
__device__ __forceinline__ ushort f2bf(float x) {
    unsigned u = __float_as_uint(x);
    unsigned r = (u + 0x7FFFu + ((u >> 16) & 1u)) >> 16;
    return (ushort)r;
}
__device__ __forceinline__ float bf2f(ushort h) { return __uint_as_float(((unsigned)h) << 16); }

// full sum over the 16-lane DPP row via row_ror rotate-accumulate (all VALU).
__device__ __forceinline__ float rowsum16(float x) {
    x += __int_as_float(__builtin_amdgcn_update_dpp(0, __float_as_int(x), 0x121, 0xF, 0xF, true)); // ror:1
    x += __int_as_float(__builtin_amdgcn_update_dpp(0, __float_as_int(x), 0x122, 0xF, 0xF, true)); // ror:2
    x += __int_as_float(__builtin_amdgcn_update_dpp(0, __float_as_int(x), 0x124, 0xF, 0xF, true)); // ror:4
    x += __int_as_float(__builtin_amdgcn_update_dpp(0, __float_as_int(x), 0x128, 0xF, 0xF, true)); // ror:8
    return x;
}

// async global->LDS, 16B per lane; LDS dest = wave-uniform base + lane*16
#define GLOAD16(GPTR, LPTR)                                                   \
    __builtin_amdgcn_global_load_lds(                                         \
        (const __attribute__((address_space(1))) unsigned*)(GPTR),            \
        (__attribute__((address_space(3))) unsigned*)(LPTR), 16, 0, 0)

// ---------------------------------------------------------------------------
// token-shift + 6 mixes; ALL six emitted as split-bf16 pairs (hi @p, lo @p+MC)
// ---------------------------------------------------------------------------
__global__ __launch_bounds__(256) void mix6_kernel(
    const float* __restrict__ x,
    const float* __restrict__ mr, const float* __restrict__ mw, const float* __restrict__ mk,
    const float* __restrict__ mv, const float* __restrict__ ma, const float* __restrict__ mg,
    ushort* __restrict__ r_sp, ushort* __restrict__ w_sp, ushort* __restrict__ k_sp,
    ushort* __restrict__ v_sp, ushort* __restrict__ a_sp, ushort* __restrict__ g_sp)
{
    int idx = blockIdx.x * 256 + threadIdx.x;  // float4 index
    int e = idx * 4;
    if (e >= Mn * Cn) return;
    int m = e / Cn;
    int c = e - m * Cn;
    int t = m & (Tn - 1);
    float4 xv = *(const float4*)(x + e);
    float4 xp = make_float4(0.f, 0.f, 0.f, 0.f);
    if (t > 0) xp = *(const float4*)(x + e - Cn);
    float4 dx = make_float4(xp.x - xv.x, xp.y - xv.y, xp.z - xv.z, xp.w - xv.w);
#define MIXSPLIT(MIXP, P)                                                     \
    {                                                                         \
        float4 mm = *(const float4*)(MIXP + c);                               \
        float4 O = make_float4(xv.x + dx.x * mm.x, xv.y + dx.y * mm.y,        \
                               xv.z + dx.z * mm.z, xv.w + dx.w * mm.w);       \
        ushort h0 = f2bf(O.x), h1 = f2bf(O.y), h2 = f2bf(O.z), h3 = f2bf(O.w);\
        ushort l0 = f2bf(O.x - bf2f(h0)), l1 = f2bf(O.y - bf2f(h1));          \
        ushort l2 = f2bf(O.z - bf2f(h2)), l3 = f2bf(O.w - bf2f(h3));          \
        *(ushort4*)(P + e) = make_ushort4(h0, h1, h2, h3);                    \
        *(ushort4*)(P + MCc + e) = make_ushort4(l0, l1, l2, l3);              \
    }
    MIXSPLIT(mr, r_sp)
    MIXSPLIT(mw, w_sp)
    MIXSPLIT(mk, k_sp)
    MIXSPLIT(mv, v_sp)
    MIXSPLIT(ma, a_sp)
    MIXSPLIT(mg, g_sp)
#undef MIXSPLIT
}

// ---------------------------------------------------------------------------
// transpose + split-convert weight [960][960] -> [N][K] hi/lo (single)
// ---------------------------------------------------------------------------
__global__ __launch_bounds__(256) void convWT_kernel(
    const float* __restrict__ W, ushort* __restrict__ Thi, ushort* __restrict__ Tlo)
{
    __shared__ float tile[32][33];
    int k0 = blockIdx.x * 32, n0 = blockIdx.y * 32;
    int tx = threadIdx.x & 31, ty = threadIdx.x >> 5;  // 32 x 8
#pragma unroll
    for (int i = 0; i < 4; ++i)
        tile[ty + 8 * i][tx] = W[(size_t)(k0 + ty + 8 * i) * 960 + n0 + tx];
    __syncthreads();
#pragma unroll
    for (int i = 0; i < 4; ++i) {
        float x = tile[tx][ty + 8 * i];
        ushort h = f2bf(x);
        ushort l = f2bf(x - bf2f(h));
        size_t o = (size_t)(n0 + ty + 8 * i) * 960 + k0 + tx;
        Thi[o] = h;
        Tlo[o] = l;
    }
}

// merged z=3: Wr->S0, Wk->S1, Wv->S2
__global__ __launch_bounds__(256) void convWT3_kernel(
    const float* __restrict__ Wr, const float* __restrict__ Wk,
    const float* __restrict__ Wv,
    ushort* __restrict__ S0, ushort* __restrict__ S1, ushort* __restrict__ S2)
{
    __shared__ float tile[32][33];
    int z = blockIdx.z;
    const float* W = (z == 0) ? Wr : (z == 1) ? Wk : Wv;
    ushort* Thi = (z == 0) ? S0 : (z == 1) ? S1 : S2;
    ushort* Tlo = Thi + (size_t)960 * 960;
    int k0 = blockIdx.x * 32, n0 = blockIdx.y * 32;
    int tx = threadIdx.x & 31, ty = threadIdx.x >> 5;
#pragma unroll
    for (int i = 0; i < 4; ++i)
        tile[ty + 8 * i][tx] = W[(size_t)(k0 + ty + 8 * i) * 960 + n0 + tx];
    __syncthreads();
#pragma unroll
    for (int i = 0; i < 4; ++i) {
        float x = tile[tx][ty + 8 * i];
        ushort h = f2bf(x);
        ushort l = f2bf(x - bf2f(h));
        size_t o = (size_t)(n0 + ty + 8 * i) * 960 + k0 + tx;
        Thi[o] = h;
        Tlo[o] = l;
    }
}

// ---------------------------------------------------------------------------
// LoRA weight prep
// ---------------------------------------------------------------------------
__global__ __launch_bounds__(256) void wprep_kernel(
    const float* __restrict__ w1, const float* __restrict__ a1,
    const float* __restrict__ v1, const float* __restrict__ g1,
    const float* __restrict__ w2, const float* __restrict__ a2,
    const float* __restrict__ v2, const float* __restrict__ g2,
    ushort* __restrict__ arena)
{
    __shared__ float tile[32][33];
    int z = blockIdx.z;
    const float* src;
    int K, N;
    size_t off;
    switch (z) {
        case 0: src = w1; K = 960; N = 64;  off = 0;      break;
        case 1: src = a1; K = 960; N = 64;  off = 122880; break;
        case 2: src = v1; K = 960; N = 32;  off = 245760; break;
        case 3: src = g1; K = 960; N = 128; off = 307200; break;
        case 4: src = w2; K = 64;  N = 960; off = 552960; break;
        case 5: src = a2; K = 64;  N = 960; off = 675840; break;
        case 6: src = v2; K = 32;  N = 960; off = 798720; break;
        default: src = g2; K = 128; N = 960; off = 860160; break;
    }
    int k0 = blockIdx.x * 32, n0 = blockIdx.y * 32;
    if (k0 >= K || n0 >= N) return;
    int tx = threadIdx.x & 31, ty = threadIdx.x >> 5;
#pragma unroll
    for (int i = 0; i < 4; ++i)
        tile[ty + 8 * i][tx] = src[(size_t)(k0 + ty + 8 * i) * N + n0 + tx];
    __syncthreads();
    ushort* Thi = arena + off;
    ushort* Tlo = arena + off + (size_t)K * N;
#pragma unroll
    for (int i = 0; i < 4; ++i) {
        float x = tile[tx][ty + 8 * i];
        ushort h = f2bf(x);
        ushort l = f2bf(x - bf2f(h));
        size_t o = (size_t)(n0 + ty + 8 * i) * K + k0 + tx;
        Thi[o] = h;
        Tlo[o] = l;
    }
}

// ---------------------------------------------------------------------------
// split-bf16 MFMA GEMM core, 256 threads / 4 waves, BM=128 BN=64 BK=32.
// NEW (this round's single change): 2-buffer COUNTED-vmcnt pipeline within
// the proven 48KB static LDS. Per iteration: vmcnt(6) retires tile ks only
// (tile ks+1's 6 DMA loads stay in flight across the barrier — never drain
// to 0 in the loop); fenced barrier; compute; lgkmcnt(0)+fenced barrier
// (all reads consumed); re-stage tile ks+2 into the buffer just freed.
// Each tile's loads now get a full iteration of compute cover instead of
// one COMPUTEK (the R23/R25 structure drained vmcnt(0) every k-step).
// ---------------------------------------------------------------------------
__device__ __forceinline__ void gemm_core(
    const ushort* __restrict__ Ahi, const ushort* __restrict__ Alo,
    const ushort* __restrict__ Bhi, const ushort* __restrict__ Blo,
    float* __restrict__ C, int ldc, int bm, int bn)
{
    __shared__ __align__(16) ushort sA[2][2][128][32];  // 32768 B
    __shared__ __align__(16) ushort sB[2][2][64][32];   // 16384 B
    const int K = 960;
    int t = threadIdx.x;
    int w = t >> 6, l = t & 63;
    int lr = l & 15, lk = l >> 4;
    int lks = lk ^ ((lr >> 1) & 3);   // swizzled read chunk

    int srow = l >> 2;
    int skc = ((l & 3) ^ ((l >> 3) & 3)) * 8;
    const ushort* gA0h = Ahi + (size_t)(bm + 32 * w + srow) * K + skc;
    const ushort* gA1h = Ahi + (size_t)(bm + 32 * w + 16 + srow) * K + skc;
    const ushort* gA0l = Alo + (size_t)(bm + 32 * w + srow) * K + skc;
    const ushort* gA1l = Alo + (size_t)(bm + 32 * w + 16 + srow) * K + skc;
    const ushort* gBh = Bhi + (size_t)(bn + 16 * w + srow) * K + skc;
    const ushort* gBl = Blo + (size_t)(bn + 16 * w + srow) * K + skc;

    f32x4 acc[2][4];
#pragma unroll
    for (int i = 0; i < 2; ++i)
#pragma unroll
        for (int j = 0; j < 4; ++j)
#pragma unroll
            for (int e = 0; e < 4; ++e) acc[i][j][e] = 0.f;

#define STAGE(BUF, KOFF)                                                      \
    {                                                                         \
        GLOAD16(gA0h + (KOFF), &sA[BUF][0][32 * w][0]);                       \
        GLOAD16(gA1h + (KOFF), &sA[BUF][0][32 * w + 16][0]);                  \
        GLOAD16(gA0l + (KOFF), &sA[BUF][1][32 * w][0]);                       \
        GLOAD16(gA1l + (KOFF), &sA[BUF][1][32 * w + 16][0]);                  \
        GLOAD16(gBh + (KOFF), &sB[BUF][0][16 * w][0]);                        \
        GLOAD16(gBl + (KOFF), &sB[BUF][1][16 * w][0]);                        \
    }
#define COMPUTEK(BUF)                                                         \
    {                                                                         \
        bf16x8 ah[2], al[2], bh[4], bl[4];                                    \
        _Pragma("unroll")                                                     \
        for (int i = 0; i < 2; ++i) {                                         \
            ah[i] = *(const bf16x8*)&sA[BUF][0][32 * w + 16 * i + lr][lks * 8];\
            al[i] = *(const bf16x8*)&sA[BUF][1][32 * w + 16 * i + lr][lks * 8];\
        }                                                                     \
        _Pragma("unroll")                                                     \
        for (int j = 0; j < 4; ++j) {                                         \
            bh[j] = *(const bf16x8*)&sB[BUF][0][16 * j + lr][lks * 8];        \
            bl[j] = *(const bf16x8*)&sB[BUF][1][16 * j + lr][lks * 8];        \
        }                                                                     \
        _Pragma("unroll")                                                     \
        for (int i = 0; i < 2; ++i)                                           \
            _Pragma("unroll")                                                 \
            for (int j = 0; j < 4; ++j) {                                     \
                acc[i][j] = __builtin_amdgcn_mfma_f32_16x16x32_bf16(          \
                    ah[i], bh[j], acc[i][j], 0, 0, 0);                        \
                acc[i][j] = __builtin_amdgcn_mfma_f32_16x16x32_bf16(          \
                    ah[i], bl[j], acc[i][j], 0, 0, 0);                        \
                acc[i][j] = __builtin_amdgcn_mfma_f32_16x16x32_bf16(          \
                    al[i], bh[j], acc[i][j], 0, 0, 0);                        \
            }                                                                 \
    }

    // prologue: 2-deep — tiles 0 and 1 in flight (12 DMA loads/wave)
    STAGE(0, 0)
    STAGE(1, 32)

    // invariant at iter top (ks<=28): outstanding = tile ks (6) + tile ks+1
    // (6); vmcnt(6) retires exactly tile ks (per-wave FIFO). ks=29: only
    // tile 29's 6 remain -> vmcnt(0). Barrier#1 collects all 4 waves'
    // quarters. Barrier#2 (after lgkmcnt(0)) releases the buffer: every
    // wave's ds_reads of buf ks&1 have completed into registers before any
    // wave issues the tile-ks+2 DMA into that same buffer.
    for (int ks = 0; ks < 30; ++ks) {
        if (ks < 29) {
            asm volatile("s_waitcnt vmcnt(6)" ::: "memory");
        } else {
            asm volatile("s_waitcnt vmcnt(0)" ::: "memory");
        }
        asm volatile("s_barrier" ::: "memory");
        __builtin_amdgcn_s_setprio(1);
        COMPUTEK(ks & 1)
        __builtin_amdgcn_s_setprio(0);
        if (ks + 2 < 30) {
            asm volatile("s_waitcnt lgkmcnt(0)" ::: "memory");
            asm volatile("s_barrier" ::: "memory");
            STAGE(ks & 1, (ks + 2) * 32)
        }
    }

#pragma unroll
    for (int i = 0; i < 2; ++i)
#pragma unroll
        for (int j = 0; j < 4; ++j)
#pragma unroll
            for (int jr = 0; jr < 4; ++jr) {
                int row = bm + 32 * w + 16 * i + lk * 4 + jr;
                int col = bn + 16 * j + lr;
                C[(size_t)row * ldc + col] = acc[i][j][jr];
            }
#undef COMPUTEK
#undef STAGE
}

// merged stage-1: z=0 r, z=1 k, z=2 v
__global__ __launch_bounds__(256) void gemm3_kernel(
    const ushort* __restrict__ XR, const ushort* __restrict__ XK,
    const ushort* __restrict__ XV,
    const ushort* __restrict__ WrS, const ushort* __restrict__ WkS,
    const ushort* __restrict__ WvS,
    float* __restrict__ oR, float* __restrict__ oK, float* __restrict__ oV)
{
    int z = blockIdx.z;
    const ushort* A = (z == 0) ? XR : (z == 1) ? XK : XV;
    const ushort* W = (z == 0) ? WrS : (z == 1) ? WkS : WvS;
    float* C = (z == 0) ? oR : (z == 1) ? oK : oV;
    gemm_core(A, A + MCc, W, W + (size_t)960 * 960, C, Cn,
              blockIdx.x * 128, blockIdx.y * 64);
}

__global__ __launch_bounds__(256) void gemm1_kernel(
    const ushort* __restrict__ Ahi, const ushort* __restrict__ Alo,
    const ushort* __restrict__ Bhi, const ushort* __restrict__ Blo,
    float* __restrict__ C, int ldc)
{
    gemm_core(Ahi, Alo, Bhi, Blo, C, ldc, blockIdx.x * 128, blockIdx.y * 64);
}

// ---------------------------------------------------------------------------
// generic split-bf16 MFMA core for LoRA (512 threads) — unchanged from R25
// ---------------------------------------------------------------------------
__device__ __forceinline__ void lora_core(
    const ushort* __restrict__ Ahi, const ushort* __restrict__ Alo, int lda,
    const ushort* __restrict__ Bhi, const ushort* __restrict__ Blo,
    float* __restrict__ C, ushort* __restrict__ Chi, ushort* __restrict__ Clo,
    int ldc, int Nvalid, int K, int act, int bn)
{
    __shared__ __align__(16) ushort sA[2][2][128][40];
    __shared__ __align__(16) ushort sB[2][2][64][40];
    int bm = blockIdx.x * 128;
    int t = threadIdx.x;
    int w = t >> 6, l = t & 63;
    int lr = l & 15, lk = l >> 4;

    int ar = t >> 2, aseg = t & 3;
    int brr = t >> 2;
    int bhl = brr >> 6, brow = brr & 63, bseg = t & 3;
    const ushort* gAh = Ahi + (size_t)(bm + ar) * lda + aseg * 8;
    const ushort* gAl = Alo + (size_t)(bm + ar) * lda + aseg * 8;
    const ushort* gB = (bhl ? Blo : Bhi) + (size_t)(bn + brow) * K + bseg * 8;

    f32x4 acc[4];
#pragma unroll
    for (int j = 0; j < 4; ++j)
#pragma unroll
        for (int e = 0; e < 4; ++e) acc[j][e] = 0.f;

    float4 rhP, rlP, rbP, rhQ, rlQ, rbQ;
#define LLOADP(KOFF)                                                          \
    {                                                                         \
        rhP = *(const float4*)(gAh + (KOFF));                                 \
        rlP = *(const float4*)(gAl + (KOFF));                                 \
        rbP = *(const float4*)(gB + (KOFF));                                  \
    }
#define LLOADQ(KOFF)                                                          \
    {                                                                         \
        rhQ = *(const float4*)(gAh + (KOFF));                                 \
        rlQ = *(const float4*)(gAl + (KOFF));                                 \
        rbQ = *(const float4*)(gB + (KOFF));                                  \
    }
#define LWRITEP(BUF)                                                          \
    {                                                                         \
        *(float4*)&sA[BUF][0][ar][aseg * 8] = rhP;                            \
        *(float4*)&sA[BUF][1][ar][aseg * 8] = rlP;                            \
        *(float4*)&sB[BUF][bhl][brow][bseg * 8] = rbP;                        \
    }
#define LWRITEQ(BUF)                                                          \
    {                                                                         \
        *(float4*)&sA[BUF][0][ar][aseg * 8] = rhQ;                            \
        *(float4*)&sA[BUF][1][ar][aseg * 8] = rlQ;                            \
        *(float4*)&sB[BUF][bhl][brow][bseg * 8] = rbQ;                        \
    }
#define LCOMPUTE(BUF)                                                         \
    {                                                                         \
        bf16x8 ah, al, bh[4], bl[4];                                          \
        ah = *(const bf16x8*)&sA[BUF][0][16 * w + lr][lk * 8];                \
        al = *(const bf16x8*)&sA[BUF][1][16 * w + lr][lk * 8];                \
        _Pragma("unroll")                                                     \
        for (int j = 0; j < 4; ++j) {                                         \
            bh[j] = *(const bf16x8*)&sB[BUF][0][16 * j + lr][lk * 8];         \
            bl[j] = *(const bf16x8*)&sB[BUF][1][16 * j + lr][lk * 8];         \
        }                                                                     \
        _Pragma("unroll")                                                     \
        for (int j = 0; j < 4; ++j) {                                         \
            acc[j] = __builtin_amdgcn_mfma_f32_16x16x32_bf16(ah, bh[j], acc[j], 0, 0, 0); \
            acc[j] = __builtin_amdgcn_mfma_f32_16x16x32_bf16(ah, bl[j], acc[j], 0, 0, 0); \
            acc[j] = __builtin_amdgcn_mfma_f32_16x16x32_bf16(al, bh[j], acc[j], 0, 0, 0); \
        }                                                                     \
    }

    int nk = K >> 5;
    LLOADP(0)
    LWRITEP(0)
    if (nk > 1) LLOADQ(32)
    asm volatile("s_waitcnt lgkmcnt(0)" ::: "memory");
    __builtin_amdgcn_s_barrier();

    int cur = 0;
    for (int ks = 0; ks < nk; ++ks) {
        int k2 = (ks + 2 < nk ? ks + 2 : nk - 1) * 32;
        if (!(ks & 1)) { LLOADP(k2) } else { LLOADQ(k2) }
        LCOMPUTE(cur)
        if (ks + 1 < nk) {
            if (!(ks & 1)) { LWRITEQ(cur ^ 1) } else { LWRITEP(cur ^ 1) }
            asm volatile("s_waitcnt lgkmcnt(0)" ::: "memory");
            __builtin_amdgcn_s_barrier();
        }
        cur ^= 1;
    }

#pragma unroll
    for (int j = 0; j < 4; ++j)
#pragma unroll
        for (int jr = 0; jr < 4; ++jr) {
            int row = bm + 16 * w + lk * 4 + jr;
            int col = bn + 16 * j + lr;
            if (col < Nvalid) {
                float v = acc[j][jr];
                if (act == 1) v = tanhf(v);
                else if (act == 2) v = sigmf(v);
                if (Chi) {
                    ushort h = f2bf(v);
                    ushort lo = f2bf(v - bf2f(h));
                    Chi[(size_t)row * ldc + col] = h;
                    Clo[(size_t)row * ldc + col] = lo;
                } else {
                    C[(size_t)row * ldc + col] = v;
                }
            }
        }
#undef LCOMPUTE
#undef LWRITEP
#undef LWRITEQ
#undef LLOADP
#undef LLOADQ
}

// LoRA-down MFMA: grid (32, 2, 4) — writes hid split pair directly
__global__ __launch_bounds__(512) void lora_down_kernel(
    const ushort* __restrict__ xw_sp, const ushort* __restrict__ xa_sp,
    const ushort* __restrict__ xv_sp, const ushort* __restrict__ xg_sp,
    const ushort* __restrict__ arena,
    ushort* __restrict__ hidHi, ushort* __restrict__ hidLo)
{
    int z = blockIdx.z;
    int bn = blockIdx.y * 64;
    const ushort* A;
    size_t off;
    int N, act, coff;
    switch (z) {
        case 0: A = xw_sp; off = 0;      N = 64;  act = 1; coff = 0;   break;
        case 1: A = xa_sp; off = 122880; N = 64;  act = 0; coff = 64;  break;
        case 2: A = xv_sp; off = 245760; N = 32;  act = 0; coff = 128; break;
        default: A = xg_sp; off = 307200; N = 128; act = 2; coff = 160; break;
    }
    if (bn >= N) return;
    lora_core(A, A + MCc, Cn, arena + off, arena + off + (size_t)960 * N,
              nullptr, hidHi + coff, hidLo + coff, 288, N, 960, act, bn);
}

// LoRA-up MFMA: grid (32, 15, 4)
__global__ __launch_bounds__(512) void lora_up_kernel(
    const ushort* __restrict__ hidHi, const ushort* __restrict__ hidLo,
    const ushort* __restrict__ arena,
    float* __restrict__ oW, float* __restrict__ oA,
    float* __restrict__ oV, float* __restrict__ oG)
{
    int z = blockIdx.z;
    int bn = blockIdx.y * 64;
    size_t off;
    int K, aoff;
    float* C;
    switch (z) {
        case 0: off = 552960; K = 64;  aoff = 0;   C = oW; break;
        case 1: off = 675840; K = 64;  aoff = 64;  C = oA; break;
        case 2: off = 798720; K = 32;  aoff = 128; C = oV; break;
        default: off = 860160; K = 128; aoff = 160; C = oG; break;
    }
    lora_core(hidHi + aoff, hidLo + aoff, 288, arena + off,
              arena + off + (size_t)K * 960, C, nullptr, nullptr,
              Cn, Cn, K, 0, bn);
}

// ---------------------------------------------------------------------------
// SEQUENCE-PARALLEL chunked scan: 8 segments (480 blocks), 16-step chunks,
// 32-step warmup (R23 proven config).
// ---------------------------------------------------------------------------
__global__ __launch_bounds__(256, 2) void scan_kernel(
    const float* __restrict__ rP, const float* __restrict__ wrawP,
    const float* __restrict__ apreP, const float* __restrict__ vsigP,
    const float* __restrict__ krawP, const float* __restrict__ vrawP,
    const float* __restrict__ vfirstP, const float* __restrict__ gP,
    const float* __restrict__ w0, const float* __restrict__ a0,
    const float* __restrict__ v0c, const float* __restrict__ kkc,
    const float* __restrict__ kac, const float* __restrict__ r_k,
    const float* __restrict__ ln_g, const float* __restrict__ ln_b,
    ushort* __restrict__ xsp)
{
    __shared__ float buf[2][7][16][64];  // 57344 B
    __shared__ float outL[16][64];       // 4096 B
    int tid = threadIdx.x;
    int q = tid >> 6, l = tid & 63;
    int blk = blockIdx.x;
    int bh = blk >> 3, seg = blk & 7;
    int bb = bh / Hn, h = bh - bb * Hn;
    size_t base = (size_t)bb * Tn * Cn + h * 64;
    int rg = l >> 4, cg = l & 15;
    int row0 = 16 * q + 4 * rg;
    int c0 = 4 * cg;

    int sstep = tid >> 4, sseg = tid & 15;
    size_t soff = base + (size_t)sstep * Cn + sseg * 4;
    int wofs = sstep * 64 + sseg * 4;
    int ccol = h * 64 + sseg * 4;

    int cbeg = (seg == 0) ? 0 : 8 * seg - 2;
    int cendc = 8 * seg + 8;
    int coutc = 8 * seg;

    float4 w0c4 = *(const float4*)(w0 + ccol);
    float4 a0c4 = *(const float4*)(a0 + ccol);
    float4 v0c4 = *(const float4*)(v0c + ccol);
    float4 kkc4 = *(const float4*)(kkc + ccol);
    float4 kac4 = *(const float4*)(kac + ccol);
    float4 rk4 = *(const float4*)(r_k + ccol);
    float4 lg4 = *(const float4*)(ln_g + ccol);
    float4 lb4 = *(const float4*)(ln_b + ccol);

    float s[4][4];
#pragma unroll
    for (int r = 0; r < 4; ++r)
#pragma unroll
        for (int c = 0; c < 4; ++c) s[r][c] = 0.f;

    float4 g_r, g_wr, g_vr, g_vf, g_vs, g_g, g_kr, g_ap;

#define LOADSTAGE(OFF)                                                        \
    g_r = *(const float4*)(rP + soff + (OFF));                                \
    g_wr = *(const float4*)(wrawP + soff + (OFF));                            \
    g_vr = *(const float4*)(vrawP + soff + (OFF));                            \
    g_vf = *(const float4*)(vfirstP + soff + (OFF));                          \
    g_vs = *(const float4*)(vsigP + soff + (OFF));                            \
    g_g = *(const float4*)(gP + soff + (OFF));                                \
    g_kr = *(const float4*)(krawP + soff + (OFF));                            \
    g_ap = *(const float4*)(apreP + soff + (OFF));

#define PARK(BN)                                                              \
    {                                                                         \
        const float E = 0.60653065971263342f;                                 \
        float4 w4;                                                            \
        w4.x = sigmf(w0c4.x + g_wr.x) * E;                                    \
        w4.y = sigmf(w0c4.y + g_wr.y) * E;                                    \
        w4.z = sigmf(w0c4.z + g_wr.z) * E;                                    \
        w4.w = sigmf(w0c4.w + g_wr.w) * E;                                    \
        float4 v4;                                                            \
        v4.x = g_vr.x + (g_vf.x - g_vr.x) * sigmf(v0c4.x + g_vs.x);           \
        v4.y = g_vr.y + (g_vf.y - g_vr.y) * sigmf(v0c4.y + g_vs.y);           \
        v4.z = g_vr.z + (g_vf.z - g_vr.z) * sigmf(v0c4.z + g_vs.z);           \
        v4.w = g_vr.w + (g_vf.w - g_vr.w) * sigmf(v0c4.w + g_vs.w);           \
        float4 a4;                                                            \
        a4.x = sigmf(a0c4.x + g_ap.x);                                        \
        a4.y = sigmf(a0c4.y + g_ap.y);                                        \
        a4.z = sigmf(a0c4.z + g_ap.z);                                        \
        a4.w = sigmf(a0c4.w + g_ap.w);                                        \
        float4 kk;                                                            \
        kk.x = g_kr.x * kkc4.x; kk.y = g_kr.y * kkc4.y;                       \
        kk.z = g_kr.z * kkc4.z; kk.w = g_kr.w * kkc4.w;                       \
        float ss = kk.x * kk.x + kk.y * kk.y + kk.z * kk.z + kk.w * kk.w;     \
        ss = rowsum16(ss);                                                    \
        float inv = 1.0f / fmaxf(sqrtf(ss), 1e-12f);                          \
        float4 ah4, bh4, kh4;                                                 \
        ah4.x = -kk.x * inv; bh4.x = kk.x * inv * a4.x;                       \
        ah4.y = -kk.y * inv; bh4.y = kk.y * inv * a4.y;                       \
        ah4.z = -kk.z * inv; bh4.z = kk.z * inv * a4.z;                       \
        ah4.w = -kk.w * inv; bh4.w = kk.w * inv * a4.w;                       \
        kh4.x = g_kr.x * (1.0f + (a4.x - 1.0f) * kac4.x);                     \
        kh4.y = g_kr.y * (1.0f + (a4.y - 1.0f) * kac4.y);                     \
        kh4.z = g_kr.z * (1.0f + (a4.z - 1.0f) * kac4.z);                     \
        kh4.w = g_kr.w * (1.0f + (a4.w - 1.0f) * kac4.w);                     \
        *(float4*)((BN) + 0 * 1024 + wofs) = g_r;                             \
        *(float4*)((BN) + 1 * 1024 + wofs) = w4;                              \
        *(float4*)((BN) + 2 * 1024 + wofs) = kh4;                             \
        *(float4*)((BN) + 3 * 1024 + wofs) = ah4;                             \
        *(float4*)((BN) + 4 * 1024 + wofs) = bh4;                             \
        *(float4*)((BN) + 5 * 1024 + wofs) = v4;                              \
        *(float4*)((BN) + 6 * 1024 + wofs) = g_g;                             \
    }

    LOADSTAGE((size_t)cbeg * 16 * Cn)
    PARK(&buf[0][0][0][0])
    asm volatile("s_waitcnt lgkmcnt(0)" ::: "memory");
    __builtin_amdgcn_s_barrier();

#define DECL2(S)                                                              \
    float4 S##a0, S##w0, S##k0, S##b0, S##r0, S##v0;                          \
    float4 S##a1, S##w1, S##k1, S##b1, S##r1, S##v1;
#define DSLOAD2(S, T)                                                         \
    S##a0 = *(const float4*)(bc + 3 * 1024 + (T) * 64 + c0);                  \
    S##w0 = *(const float4*)(bc + 1 * 1024 + (T) * 64 + c0);                  \
    S##k0 = *(const float4*)(bc + 2 * 1024 + (T) * 64 + c0);                  \
    S##b0 = *(const float4*)(bc + 4 * 1024 + (T) * 64 + c0);                  \
    S##r0 = *(const float4*)(bc + 0 * 1024 + (T) * 64 + c0);                  \
    S##v0 = *(const float4*)(bc + 5 * 1024 + (T) * 64 + row0);                \
    S##a1 = *(const float4*)(bc + 3 * 1024 + ((T) + 1) * 64 + c0);            \
    S##w1 = *(const float4*)(bc + 1 * 1024 + ((T) + 1) * 64 + c0);            \
    S##k1 = *(const float4*)(bc + 2 * 1024 + ((T) + 1) * 64 + c0);            \
    S##b1 = *(const float4*)(bc + 4 * 1024 + ((T) + 1) * 64 + c0);            \
    S##r1 = *(const float4*)(bc + 0 * 1024 + ((T) + 1) * 64 + c0);            \
    S##v1 = *(const float4*)(bc + 5 * 1024 + ((T) + 1) * 64 + row0);
#define STEP(AV, WV, KV, BV, RV, VV, T)                                       \
    {                                                                         \
        float sp0 = s[0][0] * AV.x + s[0][1] * AV.y + s[0][2] * AV.z + s[0][3] * AV.w; \
        float sp1 = s[1][0] * AV.x + s[1][1] * AV.y + s[1][2] * AV.z + s[1][3] * AV.w; \
        float sp2 = s[2][0] * AV.x + s[2][1] * AV.y + s[2][2] * AV.z + s[2][3] * AV.w; \
        float sp3 = s[3][0] * AV.x + s[3][1] * AV.y + s[3][2] * AV.z + s[3][3] * AV.w; \
        sp0 = rowsum16(sp0);                                                  \
        sp1 = rowsum16(sp1);                                                  \
        sp2 = rowsum16(sp2);                                                  \
        sp3 = rowsum16(sp3);                                                  \
        float sa[4] = {sp0, sp1, sp2, sp3};                                   \
        float vr[4] = {VV.x, VV.y, VV.z, VV.w};                               \
        float op[4];                                                          \
        _Pragma("unroll")                                                     \
        for (int r = 0; r < 4; ++r) {                                         \
            s[r][0] = s[r][0] * WV.x + sa[r] * BV.x + vr[r] * KV.x;           \
            float o = s[r][0] * RV.x;                                         \
            s[r][1] = s[r][1] * WV.y + sa[r] * BV.y + vr[r] * KV.y;           \
            o += s[r][1] * RV.y;                                              \
            s[r][2] = s[r][2] * WV.z + sa[r] * BV.z + vr[r] * KV.z;           \
            o += s[r][2] * RV.z;                                              \
            s[r][3] = s[r][3] * WV.w + sa[r] * BV.w + vr[r] * KV.w;           \
            o += s[r][3] * RV.w;                                              \
            op[r] = rowsum16(o);                                              \
        }                                                                     \
        if (cg == 0)                                                          \
            *(float4*)&outL[T][row0] = make_float4(op[0], op[1], op[2], op[3]); \
    }

    DECL2(A) DECL2(B)

    int cur = 0;
    for (int c = cbeg; c < cendc; ++c) {
        const float* bc = &buf[cur][0][0][0];
        {
            int cnxt = (c + 1 < cendc) ? c + 1 : c;
            LOADSTAGE((size_t)cnxt * 16 * Cn)
        }

        DSLOAD2(A, 0)
#pragma unroll
        for (int it = 0; it < 4; ++it) {
            DSLOAD2(B, 4 * it + 2)
            STEP(Aa0, Aw0, Ak0, Ab0, Ar0, Av0, 4 * it + 0)
            STEP(Aa1, Aw1, Ak1, Ab1, Ar1, Av1, 4 * it + 1)
            if (it < 3) { DSLOAD2(A, 4 * it + 4) }
            STEP(Ba0, Bw0, Bk0, Bb0, Br0, Bv0, 4 * it + 2)
            STEP(Ba1, Bw1, Bk1, Bb1, Br1, Bv1, 4 * it + 3)
        }

        PARK(&buf[cur ^ 1][0][0][0])
        asm volatile("s_waitcnt lgkmcnt(0)" ::: "memory");
        __builtin_amdgcn_s_barrier();

        if (c >= coutc) {
            float4 o4 = *(const float4*)&outL[sstep][4 * sseg];
            float4 r4 = *(const float4*)(bc + 0 * 1024 + sstep * 64 + 4 * sseg);
            float4 k4 = *(const float4*)(bc + 2 * 1024 + sstep * 64 + 4 * sseg);
            float4 v4 = *(const float4*)(bc + 5 * 1024 + sstep * 64 + 4 * sseg);
            float4 gg4 = *(const float4*)(bc + 6 * 1024 + sstep * 64 + 4 * sseg);
            float m1 = o4.x + o4.y + o4.z + o4.w;
            float m2 = o4.x * o4.x + o4.y * o4.y + o4.z * o4.z + o4.w * o4.w;
            float bd = r4.x * k4.x * rk4.x + r4.y * k4.y * rk4.y +
                       r4.z * k4.z * rk4.z + r4.w * k4.w * rk4.w;
            m1 = rowsum16(m1);
            m2 = rowsum16(m2);
            bd = rowsum16(bd);
            float mean = m1 * (1.f / 64.f);
            float var = m2 * (1.f / 64.f) - mean * mean;
            float is = rsqrtf(var + 0.00064f);
            float xo0 = ((o4.x - mean) * is * lg4.x + lb4.x + bd * v4.x) * gg4.x;
            float xo1 = ((o4.y - mean) * is * lg4.y + lb4.y + bd * v4.y) * gg4.y;
            float xo2 = ((o4.z - mean) * is * lg4.z + lb4.z + bd * v4.z) * gg4.z;
            float xo3 = ((o4.w - mean) * is * lg4.w + lb4.w + bd * v4.w) * gg4.w;
            ushort h0 = f2bf(xo0), h1 = f2bf(xo1), h2 = f2bf(xo2), h3 = f2bf(xo3);
            ushort l0 = f2bf(xo0 - bf2f(h0)), l1 = f2bf(xo1 - bf2f(h1));
            ushort l2 = f2bf(xo2 - bf2f(h2)), l3 = f2bf(xo3 - bf2f(h3));
            size_t gt = (size_t)c * 16 + sstep;
            size_t eo = base + gt * Cn + 4 * sseg;
            *(ushort4*)(xsp + eo) = make_ushort4(h0, h1, h2, h3);
            *(ushort4*)(xsp + MCc + eo) = make_ushort4(l0, l1, l2, l3);
        }
        __builtin_amdgcn_s_barrier();
        cur ^= 1;
    }
#undef STEP
#undef DSLOAD2
#undef DECL2
#undef PARK
#undef LOADSTAGE
}

// ---------------------------------------------------------------------------
extern "C" void kernel_launch(void* const* d_in, const int* in_sizes, int n_in,
                              void* d_out, int out_size, void* d_ws, size_t ws_size,
                              hipStream_t stream)
{
    const float* x       = (const float*)d_in[0];
    const float* v_first = (const float*)d_in[1];
    const float* x_r     = (const float*)d_in[2];
    const float* x_w     = (const float*)d_in[3];
    const float* x_k     = (const float*)d_in[4];
    const float* x_v     = (const float*)d_in[5];
    const float* x_a     = (const float*)d_in[6];
    const float* x_g     = (const float*)d_in[7];
    const float* w0      = (const float*)d_in[8];
    const float* w1      = (const float*)d_in[9];
    const float* w2      = (const float*)d_in[10];
    const float* a0      = (const float*)d_in[11];
    const float* a1      = (const float*)d_in[12];
    const float* a2      = (const float*)d_in[13];
    const float* v0c     = (const float*)d_in[14];
    const float* v1      = (const float*)d_in[15];
    const float* v2      = (const float*)d_in[16];
    const float* g1w     = (const float*)d_in[17];
    const float* g2w     = (const float*)d_in[18];
    const float* k_k     = (const float*)d_in[19];
    const float* k_a     = (const float*)d_in[20];
    const float* r_k     = (const float*)d_in[21];
    const float* Wr      = (const float*)d_in[22];
    const float* Wk      = (const float*)d_in[23];
    const float* Wv      = (const float*)d_in[24];
    const float* Wo      = (const float*)d_in[25];
    const float* ln_g    = (const float*)d_in[26];
    const float* ln_b    = (const float*)d_in[27];
    float* out = (float*)d_out;

    float* ws = (float*)d_ws;
    float* B0 = ws + 0 * MCc;  // xr split pair -> wraw f32
    float* B1 = ws + 1 * MCc;  // xw split pair -> vsigp f32
    float* B2 = ws + 2 * MCc;  // xk split pair -> apre f32
    float* B3 = ws + 3 * MCc;  // scratch: hid split + arena + Wk/Wv splits
    float* B4 = ws + 4 * MCc;  // xa split pair -> xog split pair (scan out)
    float* B5 = ws + 5 * MCc;  // xg split pair -> g f32
    float* B6 = ws + 6 * MCc;  // r f32
    float* B7 = ws + 7 * MCc;  // k raw f32
    float* B8 = ws + 8 * MCc;  // v raw f32
    float* hid = ws + 9 * MCc; // scratch: Wr/Wo split

    ushort* XRsp = (ushort*)B0;
    ushort* XWsp = (ushort*)B1;
    ushort* XKsp = (ushort*)B2;
    ushort* XVsp = (ushort*)out;  // d_out scratch until stage 5
    ushort* XAsp = (ushort*)B4;
    ushort* XGsp = (ushort*)B5;
    ushort* S3 = (ushort*)B3;
    ushort* hidHi = S3;                     // 1,179,648
    ushort* hidLo = S3 + 1179648;           // 1,179,648
    ushort* arena = S3 + 2359296;           // 1,105,920
    ushort* WkS = S3 + 3465216;             // 1,843,200
    ushort* WvS = S3 + 5308416;             // 1,843,200 (ends 7,151,616 < 7,864,320)
    ushort* WrS = (ushort*)hid;             // 1,843,200 < 2,359,296 cap
    ushort* Whi = (ushort*)hid;             // Wo split later
    ushort* Wlo = Whi + (size_t)960 * 960;
    ushort* Xsp = (ushort*)B4;              // scan output split pair

    mix6_kernel<<<3840, 256, 0, stream>>>(x, x_r, x_w, x_k, x_v, x_a, x_g,
                                          XRsp, XWsp, XKsp, XVsp, XAsp, XGsp);
    wprep_kernel<<<dim3(30, 30, 8), 256, 0, stream>>>(w1, a1, v1, g1w,
                                                      w2, a2, v2, g2w, arena);
    // stage 1: all three weight splits in one dispatch, then merged GEMM
    convWT3_kernel<<<dim3(30, 30, 3), 256, 0, stream>>>(Wr, Wk, Wv,
                                                        WrS, WkS, WvS);
    gemm3_kernel<<<dim3(32, 15, 3), 256, 0, stream>>>(XRsp, XKsp, XVsp,
                                                      WrS, WkS, WvS,
                                                      B6, B7, B8);
    // stage 2: LoRA-down via MFMA (fused tanh/sigmoid + split-pair output)
    lora_down_kernel<<<dim3(32, 2, 4), 512, 0, stream>>>(XWsp, XAsp, XVsp, XGsp,
                                                         arena, hidHi, hidLo);
    // stage 3: LoRA-up via MFMA -> B0=wraw, B2=apre, B1=vsigp, B5=g
    lora_up_kernel<<<dim3(32, 15, 4), 512, 0, stream>>>(hidHi, hidLo, arena,
                                                        B0, B2, B1, B5);
    // Wo split (hid scratch free after gemm3 consumed WrS)
    convWT_kernel<<<dim3(30, 30), 256, 0, stream>>>(Wo, Whi, Wlo);
    // stage 4: sequence-parallel scan, 8 segments (32-step warmup),
    // fused stage3e + norm/bonus/gate -> split pair in B4
    scan_kernel<<<480, 256, 0, stream>>>(B6, B0, B2, B1, B7, B8, v_first, B5,
                                         w0, a0, v0c, k_k, k_a,
                                         r_k, ln_g, ln_b, Xsp);
    // stage 5: output projection
    gemm1_kernel<<<dim3(32, 15), 256, 0, stream>>>(Xsp, Xsp + MCc, Whi, Wlo,
                                                   out, Cn);
}